// Round 16
// baseline (189.456 us; speedup 1.0000x reference)
//
#include <hip/hip_runtime.h>

#define BB 8
#define CC 512
#define NT 4096
#define GG 8
#define CPG 64
#define EPSF 1e-6f
#define SQK 0.04419417382415922f  // 1/sqrt(512)

typedef __attribute__((ext_vector_type(8))) short bf16x8;
typedef __attribute__((ext_vector_type(4))) float f32x4;

// ws offsets (float units)
#define OFF_RED  0
#define OFF_PB2  4096
#define OFF_IZ   270336
#define OFF_WKV  274432
#define OFF_PWB  536576
#define OFF_WQT  667648
#define OFF_MB   798720
#define OFF_PBF  1847296
#define OFF_CTXB 2895872
#define OFF_PCTX 3944448
#define OFF_HT   12333056
#define OFF_KVB  20721664

__device__ __forceinline__ ushort f2bf(float f) {
  union { float f; uint u; } v; v.f = f;
  uint r = (v.u + 0x7fffu + ((v.u >> 16) & 1u)) >> 16;
  return (ushort)r;
}
__device__ __forceinline__ float bf2f(ushort h) {
  union { uint u; float f; } v; v.u = ((uint)h) << 16;
  return v.f;
}
__device__ __forceinline__ uint pk(float a, float b) {
  return (uint)f2bf(a) | ((uint)f2bf(b) << 16);
}
__device__ __forceinline__ void gload16(const ushort* g, ushort* l) {
  __builtin_amdgcn_global_load_lds((const __attribute__((address_space(1))) void*)g,
                                   (__attribute__((address_space(3))) void*)l, 16, 0, 0);
}
#define KSWZ(kofs, row) ((kofs) ^ ((((row) >> 1) & 3) << 3))

// ---------------- GN stats: partial sums (512 blocks) ----------------
__global__ __launch_bounds__(256) void gn_stats1(const float* __restrict__ x,
                                                 float* __restrict__ red) {
  int bg = blockIdx.y, chunk = blockIdx.x;
  const float4* p4 = (const float4*)(x + (size_t)bg * (CPG * NT) + (size_t)chunk * 32768);
  int tid = threadIdx.x;
  float s = 0.f, sq = 0.f;
  for (int i = tid; i < 8192; i += 256) {
    float4 v = p4[i];
    s  += v.x + v.y + v.z + v.w;
    sq += v.x * v.x + v.y * v.y + v.z * v.z + v.w * v.w;
  }
  for (int off = 32; off > 0; off >>= 1) {
    s  += __shfl_down(s, off);
    sq += __shfl_down(sq, off);
  }
  __shared__ float ls[4], lq[4];
  int wid = tid >> 6, lane = tid & 63;
  if (lane == 0) { ls[wid] = s; lq[wid] = sq; }
  __syncthreads();
  if (tid == 0) {
    red[(bg * 8 + chunk) * 2]     = ls[0] + ls[1] + ls[2] + ls[3];
    red[(bg * 8 + chunk) * 2 + 1] = lq[0] + lq[1] + lq[2] + lq[3];
  }
}

// ---------------- weight converts: kv rows (1024) + proj_w -> bf16 ---------
__global__ __launch_bounds__(256) void wconv2(const float* __restrict__ qkv_w,
                                              const float* __restrict__ proj_w,
                                              ushort* __restrict__ wkvb,
                                              ushort* __restrict__ pwb) {
  int bid = blockIdx.x;
  if (bid < 512) {
    int idx = (bid * 256 + threadIdx.x) * 4;
    float4 v = *(const float4*)(qkv_w + (size_t)CC * CC + idx);  // k+v rows
    *(uint2*)(wkvb + idx) = make_uint2(pk(v.x, v.y), pk(v.z, v.w));
  } else {
    int idx = ((bid - 512) * 256 + threadIdx.x) * 4;
    float4 v = *(const float4*)(proj_w + idx);
    *(uint2*)(pwb + idx) = make_uint2(pk(v.x, v.y), pk(v.z, v.w));
  }
}

// ---------------- Wq^T bf16: wqT[c][d] = qkv_w[d][c] (q rows) --------------
__global__ __launch_bounds__(256) void wqt_kernel(const float* __restrict__ qkv_w,
                                                  ushort* __restrict__ wqT) {
  __shared__ float t[32][33];
  int d0 = blockIdx.y * 32, c0 = blockIdx.x * 32;
  int tid = threadIdx.x;
  int r = tid >> 3, c4 = (tid & 7) * 4;
  float4 v = *(const float4*)(qkv_w + (size_t)(d0 + r) * CC + c0 + c4);
  t[r][c4] = v.x; t[r][c4 + 1] = v.y; t[r][c4 + 2] = v.z; t[r][c4 + 3] = v.w;
  __syncthreads();
  int r2 = tid >> 3, d4 = (tid & 7) * 4;
  uint w0 = pk(t[d4][r2], t[d4 + 1][r2]);
  uint w1 = pk(t[d4 + 2][r2], t[d4 + 3][r2]);
  *(uint2*)&wqT[(size_t)(c0 + r2) * CC + d0 + d4] = make_uint2(w0, w1);
}

// ---------------- h^T in bf16 (with inline GN finalize) --------------------
__global__ __launch_bounds__(256) void ht_kernel(
    const float* __restrict__ x, const float* __restrict__ red,
    const float* __restrict__ gn_scale, const float* __restrict__ gn_bias,
    ushort* __restrict__ hT) {
  __shared__ float ts[64][68];
  __shared__ float la[64], lb[64];
  int b = blockIdx.z, g = blockIdx.y, n0 = blockIdx.x * 64;
  int c0 = g * 64;
  int tid = threadIdx.x;
  if (tid == 0) {
    int bg = b * 8 + g;
    float s = 0.f, sq = 0.f;
#pragma unroll
    for (int i = 0; i < 8; i++) {
      s  += red[(bg * 8 + i) * 2];
      sq += red[(bg * 8 + i) * 2 + 1];
    }
    float mean = s / (float)(CPG * NT);
    float var  = sq / (float)(CPG * NT) - mean * mean;
    ts[0][0] = mean; ts[0][1] = rsqrtf(var + EPSF);
  }
  __syncthreads();
  if (tid < 64) {
    float mean = ts[0][0], rstd = ts[0][1];
    float a = gn_scale[c0 + tid] * rstd;
    la[tid] = a;
    lb[tid] = gn_bias[c0 + tid] - mean * a;
  }
  __syncthreads();
  int tn = (tid & 15) * 4, tc = tid >> 4;
#pragma unroll
  for (int it = 0; it < 4; it++) {
    int c = tc + it * 16;
    float a  = la[c];
    float bb = lb[c];
    float4 v = *(const float4*)(x + ((size_t)(b * CC + c0 + c)) * NT + n0 + tn);
    ts[c][tn]     = a * v.x + bb;
    ts[c][tn + 1] = a * v.y + bb;
    ts[c][tn + 2] = a * v.z + bb;
    ts[c][tn + 3] = a * v.w + bb;
  }
  __syncthreads();
#pragma unroll
  for (int it = 0; it < 2; it++) {
    int idx = tid + it * 256;
    int n = idx >> 3, c8 = (idx & 7) * 8;
    uint w[4];
#pragma unroll
    for (int j = 0; j < 4; j++)
      w[j] = pk(ts[c8 + 2 * j][n], ts[c8 + 2 * j + 1][n]);
    *(uint4*)&hT[((size_t)b * NT + n0 + n) * CC + c0 + c8] = make_uint4(w[0], w[1], w[2], w[3]);
  }
}

// ===== 128x128 loop: BK=64, 8 waves (2Mx4N, wave tile 64x32), 64KB LDS =====
// 2 blocks/CU -> cross-block overlap hides staging/epilogue serial phases
// (measured win on final_gemm, R15). Swizzle: pre-swizzled global col +
// same XOR on ds_read (0 conflicts, R10-verified family).
__device__ __forceinline__ void stage128(const ushort* __restrict__ G, ushort* L,
                                         int LD, int tid) {
#pragma unroll
  for (int s = 0; s < 2; s++) {
    int row = s * 64 + (tid >> 3);
    int gcol = ((tid & 7) ^ (row & 7)) * 8;  // pre-swizzled global col
    gload16(G + (size_t)row * LD + gcol, L + s * 4096 + (tid >> 6) * 512);
  }
}

template <int NTILES>
__device__ __forceinline__ void mfma128(const ushort* __restrict__ A,
                                        const ushort* __restrict__ B,
                                        int LDA, int LDB, ushort* As, ushort* Bs,
                                        int tid, f32x4 acc[4][2]) {
  int wave = tid >> 6, lane = tid & 63;
  int wr = wave >> 2, wc = wave & 3;
  stage128(A, As, LDA, tid);
  stage128(B, Bs, LDB, tid);
  const ushort* gA = A + 64;
  const ushort* gB = B + 64;
  int rowA = wr * 64 + (lane & 15);
  int rowB = wc * 32 + (lane & 15);
  int kg0 = lane >> 4;
#pragma unroll 1
  for (int t = 0; t < NTILES; t++) {
    __builtin_amdgcn_s_barrier();
    asm volatile("" ::: "memory");
    if (t + 1 < NTILES) {
      stage128(gA, As + ((t + 1) & 1) * 8192, LDA, tid);
      stage128(gB, Bs + ((t + 1) & 1) * 8192, LDB, tid);
      gA += 64; gB += 64;
      asm volatile("s_waitcnt vmcnt(4)" ::: "memory");  // current tile landed
    } else {
      asm volatile("s_waitcnt vmcnt(0)" ::: "memory");
    }
    __builtin_amdgcn_s_barrier();
    asm volatile("" ::: "memory");
    const ushort* Ab = As + (t & 1) * 8192;
    const ushort* Bb = Bs + (t & 1) * 8192;
#pragma unroll
    for (int kk = 0; kk < 2; kk++) {
      int kg = kg0 + kk * 4;
      bf16x8 bfr[2];
#pragma unroll
      for (int ni = 0; ni < 2; ni++) {
        int r = rowB + ni * 16;
        bfr[ni] = *(const bf16x8*)(Bb + r * 64 + ((kg ^ (r & 7)) << 3));
      }
#pragma unroll
      for (int mi = 0; mi < 4; mi++) {
        int r = rowA + mi * 16;
        bf16x8 afr = *(const bf16x8*)(Ab + r * 64 + ((kg ^ (r & 7)) << 3));
#pragma unroll
        for (int ni = 0; ni < 2; ni++)
          acc[mi][ni] = __builtin_amdgcn_mfma_f32_16x16x32_bf16(afr, bfr[ni], acc[mi][ni], 0, 0, 0);
      }
    }
  }
}

// ------- 64x64 MFMA mainloop (m/p GEMMs), unchanged ------------------------
template <int KTOT, int LDA, int LDB>
__device__ __forceinline__ void mfma_loop64(const ushort* __restrict__ A,
                                            const ushort* __restrict__ B,
                                            ushort* As, ushort* Bs, int tid,
                                            f32x4 acc[2][2]) {
  int wave = tid >> 6, lane = tid & 63;
  int srow = tid >> 2;
  int kofs = KSWZ((tid & 3) * 8, srow & 15);
  const ushort* ga = A + (size_t)srow * LDA + kofs;
  const ushort* gb = B + (size_t)srow * LDB + kofs;
  int lo = wave * 512;
  int wm = (wave >> 1) * 32, wn = (wave & 1) * 32;
  int rowl = lane & 15;
  int kread = KSWZ((lane >> 4) * 8, rowl);
  int aoff = (wm + rowl) * 32 + kread;
  int boff = (wn + rowl) * 32 + kread;
  constexpr int NIT = KTOT / 32;
  gload16(ga, As + lo); gload16(gb, Bs + lo);
  ga += 32; gb += 32;
#pragma unroll 1
  for (int t = 0; t < NIT; t++) {
    int cb = (t & 1) * 2048;
    int nb = 2048 - cb;
    if (t + 1 < NIT) {
      gload16(ga, As + nb + lo); gload16(gb, Bs + nb + lo);
      ga += 32; gb += 32;
      asm volatile("s_waitcnt vmcnt(2)" ::: "memory");
    } else {
      asm volatile("s_waitcnt vmcnt(0)" ::: "memory");
    }
    __builtin_amdgcn_s_barrier();
    asm volatile("" ::: "memory");
    bf16x8 a[2], b[2];
#pragma unroll
    for (int m = 0; m < 2; m++) a[m] = *(const bf16x8*)(As + cb + aoff + m * 512);
#pragma unroll
    for (int n = 0; n < 2; n++) b[n] = *(const bf16x8*)(Bs + cb + boff + n * 512);
#pragma unroll
    for (int m = 0; m < 2; m++)
#pragma unroll
      for (int n = 0; n < 2; n++)
        acc[m][n] = __builtin_amdgcn_mfma_f32_16x16x32_bf16(a[m], b[n], acc[m][n], 0, 0, 0);
    asm volatile("" ::: "memory");
    __builtin_amdgcn_s_barrier();
    asm volatile("" ::: "memory");
  }
}

// --- kv GEMM bf16 (128^2, 2 blocks/CU) + fused exp on k-rows ---------------
__global__ __launch_bounds__(512) void kv_gemm_bf16(
    const ushort* __restrict__ wkvb, const ushort* __restrict__ hT,
    const float* __restrict__ qkv_b, ushort* __restrict__ kvb) {
  extern __shared__ ushort lds[];
  ushort* As = lds;
  ushort* Bs = lds + 2 * 8192;
  int b = blockIdx.z, n0 = blockIdx.x * 128, m0 = blockIdx.y * 128;
  int tid = threadIdx.x;
  f32x4 acc[4][2] = {{{0.f, 0.f, 0.f, 0.f}}};
  mfma128<8>(wkvb + (size_t)m0 * CC, hT + (size_t)b * NT * CC + (size_t)n0 * CC,
             CC, CC, As, Bs, tid, acc);
  int wave = tid >> 6, lane = tid & 63;
  int wr = wave >> 2, wc = wave & 3;
  int col = lane & 15, rb = (lane >> 4) * 4;
  bool isK = (m0 < 512);
#pragma unroll
  for (int mi = 0; mi < 4; mi++)
#pragma unroll
    for (int j = 0; j < 4; j++) {
      int gm = m0 + wr * 64 + mi * 16 + rb + j;
      float bias = qkv_b[CC + gm];
      ushort* orow = kvb + ((size_t)(b * 1024 + gm)) * NT + n0 + wc * 32 + col;
#pragma unroll
      for (int ni = 0; ni < 2; ni++) {
        float val = acc[mi][ni][j] + bias;
        if (isK) val = __expf(val);  // softmax shift-invariant; |k|<~6
        orow[ni * 16] = f2bf(val);
      }
    }
}

// ---------------- invZ[b*512+d] = 1 / sum_n ek[d,n] (reads rounded ek) -----
__global__ __launch_bounds__(256) void zred(const ushort* __restrict__ kvb,
                                            float* __restrict__ invZ) {
  int row = blockIdx.x;  // b*512 + d
  int b = row >> 9, d = row & 511;
  const ushort* p = kvb + ((size_t)(b * 1024 + d)) * NT;
  int tid = threadIdx.x;
  uint4 r0 = *(const uint4*)(p + tid * 16);
  uint4 r1 = *(const uint4*)(p + tid * 16 + 8);
  uint w[8] = {r0.x, r0.y, r0.z, r0.w, r1.x, r1.y, r1.z, r1.w};
  float s = 0.f;
#pragma unroll
  for (int i = 0; i < 8; i++) {
    union { uint u; float f; } lo, hi;
    lo.u = w[i] << 16; hi.u = w[i] & 0xffff0000u;
    s += lo.f + hi.f;
  }
  for (int off = 32; off > 0; off >>= 1) s += __shfl_down(s, off);
  __shared__ float red[4];
  int wid = tid >> 6, lane = tid & 63;
  if (lane == 0) red[wid] = s;
  __syncthreads();
  if (tid == 0) invZ[row] = 1.f / (red[0] + red[1] + red[2] + red[3]);
}

// --- ctx split-K (128^2, 2 blocks/CU): pctx[b,s,d,e] = sum_{n in s} ek v ---
__global__ __launch_bounds__(512) void ctx_gemm_split(
    const ushort* __restrict__ kvb, ushort* __restrict__ pctx) {
  extern __shared__ ushort lds[];
  ushort* As = lds;
  ushort* Bs = lds + 2 * 8192;
  int e0 = blockIdx.x * 128, d0 = blockIdx.y * 128;
  int bz = blockIdx.z, b = bz >> 3, s = bz & 7;
  int tid = threadIdx.x;
  f32x4 acc[4][2] = {{{0.f, 0.f, 0.f, 0.f}}};
  const ushort* K = kvb + (size_t)b * 1024 * NT + (size_t)d0 * NT + s * 512;
  const ushort* V = kvb + ((size_t)b * 1024 + 512) * NT + (size_t)e0 * NT + s * 512;
  mfma128<8>(K, V, NT, NT, As, Bs, tid, acc);
  int wave = tid >> 6, lane = tid & 63;
  int wr = wave >> 2, wc = wave & 3;
  int col = lane & 15, rb = (lane >> 4) * 4;
#pragma unroll
  for (int mi = 0; mi < 4; mi++)
#pragma unroll
    for (int j = 0; j < 4; j++) {
      int gd = d0 + wr * 64 + mi * 16 + rb + j;
      ushort* orow = pctx + ((size_t)(b * 8 + s) * CC + gd) * CC + e0 + wc * 32 + col;
#pragma unroll
      for (int ni = 0; ni < 2; ni++)
        orow[ni * 16] = f2bf(acc[mi][ni][j]);
    }
}

// ---------------- reduce splits + row-normalize -> bf16 ctx ----------------
__global__ __launch_bounds__(256) void ctx_red(const ushort* __restrict__ pctx,
                                               const float* __restrict__ invZ,
                                               ushort* __restrict__ ctxb) {
  int t = blockIdx.x * 256 + threadIdx.x;
  int b = t >> 15;
  int r = (t & 32767) * 8;
  int d = r >> 9;
  float iz = invZ[b * 512 + d];
  const ushort* base = pctx + (size_t)b * 8 * 262144 + r;
  float f[8] = {};
#pragma unroll
  for (int s = 0; s < 8; s++) {
    uint4 v = *(const uint4*)(base + (size_t)s * 262144);
    uint w[4] = {v.x, v.y, v.z, v.w};
#pragma unroll
    for (int j = 0; j < 4; j++) {
      union { uint u; float f; } lo, hi;
      lo.u = w[j] << 16; hi.u = w[j] & 0xffff0000u;
      f[2 * j] += lo.f; f[2 * j + 1] += hi.f;
    }
  }
  uint o[4];
#pragma unroll
  for (int j = 0; j < 4; j++) o[j] = pk(f[2 * j] * iz, f[2 * j + 1] * iz);
  *(uint4*)(ctxb + (size_t)b * 262144 + r) = make_uint4(o[0], o[1], o[2], o[3]);
}

// ---------------- M GEMM: Mb[b,o,d] = SQK * sum_e pw[o,e] ctx[b,d,e] -------
__global__ __launch_bounds__(256) void m_gemm_bf16(
    const ushort* __restrict__ pwb, const ushort* __restrict__ ctxb,
    ushort* __restrict__ Mb) {
  __shared__ ushort As[4096], Bs[4096];
  int b = blockIdx.z, d0 = blockIdx.x * 64, o0 = blockIdx.y * 64;
  int tid = threadIdx.x;
  f32x4 acc[2][2] = {{{0.f, 0.f, 0.f, 0.f}}};
  mfma_loop64<CC, CC, CC>(pwb + (size_t)o0 * CC,
                          ctxb + (size_t)b * CC * CC + (size_t)d0 * CC, As, Bs, tid, acc);
  int wave = tid >> 6, lane = tid & 63;
  int wm = (wave >> 1) * 32, wn = (wave & 1) * 32;
  int col = lane & 15, rb = (lane >> 4) * 4;
#pragma unroll
  for (int m = 0; m < 2; m++)
#pragma unroll
    for (int n = 0; n < 2; n++)
#pragma unroll
      for (int j = 0; j < 4; j++) {
        int go = o0 + wm + m * 16 + rb + j;
        int gd = d0 + wn + n * 16 + col;
        Mb[((size_t)b * CC + go) * CC + gd] = f2bf(acc[m][n][j] * SQK);
      }
}

// ---------------- P GEMM: Pb[b,o,c] = sum_d Mb[b,o,d] wqT[c,d] -------------
__global__ __launch_bounds__(256) void p_gemm_bf16(
    const ushort* __restrict__ Mb, const ushort* __restrict__ wqT,
    ushort* __restrict__ Pb) {
  __shared__ ushort As[4096], Bs[4096];
  int b = blockIdx.z, c0 = blockIdx.x * 64, o0 = blockIdx.y * 64;
  int tid = threadIdx.x;
  f32x4 acc[2][2] = {{{0.f, 0.f, 0.f, 0.f}}};
  mfma_loop64<CC, CC, CC>(Mb + (size_t)b * CC * CC + (size_t)o0 * CC,
                          wqT + (size_t)c0 * CC, As, Bs, tid, acc);
  int wave = tid >> 6, lane = tid & 63;
  int wm = (wave >> 1) * 32, wn = (wave & 1) * 32;
  int col = lane & 15, rb = (lane >> 4) * 4;
#pragma unroll
  for (int m = 0; m < 2; m++)
#pragma unroll
    for (int n = 0; n < 2; n++)
#pragma unroll
      for (int j = 0; j < 4; j++) {
        int go = o0 + wm + m * 16 + rb + j;
        int gc = c0 + wn + n * 16 + col;
        Pb[((size_t)b * CC + go) * CC + gc] = f2bf(acc[m][n][j]);
      }
}

// ---------------- pb2[b,o] = sum_d Mb[b,o,d]*bq[d] + proj_b[o] -------------
__global__ __launch_bounds__(256) void pb2_kernel(
    const ushort* __restrict__ Mb, const float* __restrict__ qkv_b,
    const float* __restrict__ proj_b, float* __restrict__ pb2) {
  int b = blockIdx.x, og = blockIdx.y;
  int r = og * 64 + (threadIdx.x >> 2);
  int q = threadIdx.x & 3;
  const ushort* Mr = Mb + ((size_t)(b * CC + r)) * CC + q * 128;
  const float* bq = qkv_b + q * 128;
  float s = 0.f;
#pragma unroll
  for (int i = 0; i < 16; i++) {
    uint4 v = *(const uint4*)(Mr + i * 8);
    uint w[4] = {v.x, v.y, v.z, v.w};
#pragma unroll
    for (int j = 0; j < 4; j++) {
      union { uint u; float f; } lo, hi;
      lo.u = w[j] << 16; hi.u = w[j] & 0xffff0000u;
      s += lo.f * bq[i * 8 + 2 * j] + hi.f * bq[i * 8 + 2 * j + 1];
    }
  }
  s += __shfl_xor(s, 1);
  s += __shfl_xor(s, 2);
  if (q == 0) pb2[b * CC + r] = s + proj_b[r];
}

// --- final GEMM (128^2, 8-wave, 2 blocks/CU): out = x + P@h + pb2 ----------
__global__ __launch_bounds__(512) void final_gemm_bf16(
    const float* __restrict__ x, const ushort* __restrict__ Pb,
    const ushort* __restrict__ hT, const float* __restrict__ pb2,
    float* __restrict__ out) {
  extern __shared__ ushort lds[];
  ushort* As = lds;
  ushort* Bs = lds + 2 * 8192;
  int b = blockIdx.z, n0 = blockIdx.x * 128, m0 = blockIdx.y * 128;
  int tid = threadIdx.x;
  f32x4 acc[4][2] = {{{0.f, 0.f, 0.f, 0.f}}};
  mfma128<8>(Pb + (size_t)b * CC * CC + (size_t)m0 * CC,
             hT + (size_t)b * NT * CC + (size_t)n0 * CC, CC, CC, As, Bs, tid, acc);
  int wave = tid >> 6, lane = tid & 63;
  int wr = wave >> 2, wc = wave & 3;
  int col = lane & 15, rb = (lane >> 4) * 4;
#pragma unroll
  for (int mi = 0; mi < 4; mi++)
#pragma unroll
    for (int j = 0; j < 4; j++) {
      int gm = m0 + wr * 64 + mi * 16 + rb + j;
      float bias = pb2[b * CC + gm];
      size_t rowoff = ((size_t)(b * CC + gm)) * NT + n0 + wc * 32 + col;
#pragma unroll
      for (int ni = 0; ni < 2; ni++)
        out[rowoff + ni * 16] = acc[mi][ni][j] + bias + x[rowoff + ni * 16];
    }
}

extern "C" void kernel_launch(void* const* d_in, const int* in_sizes, int n_in,
                              void* d_out, int out_size, void* d_ws, size_t ws_size,
                              hipStream_t stream) {
  const float* x        = (const float*)d_in[0];
  const float* qkv_w    = (const float*)d_in[1];
  const float* qkv_b    = (const float*)d_in[2];
  const float* proj_w   = (const float*)d_in[3];
  const float* proj_b   = (const float*)d_in[4];
  const float* gn_scale = (const float*)d_in[5];
  const float* gn_bias  = (const float*)d_in[6];
  float* out = (float*)d_out;
  float* ws  = (float*)d_ws;

  float*  red   = ws + OFF_RED;
  float*  pb2   = ws + OFF_PB2;
  float*  invZ  = ws + OFF_IZ;
  ushort* wkvb  = (ushort*)(ws + OFF_WKV);
  ushort* pwb   = (ushort*)(ws + OFF_PWB);
  ushort* wqT   = (ushort*)(ws + OFF_WQT);
  ushort* Mb    = (ushort*)(ws + OFF_MB);
  ushort* Pb    = (ushort*)(ws + OFF_PBF);
  ushort* ctxb  = (ushort*)(ws + OFF_CTXB);
  ushort* pctx  = (ushort*)(ws + OFF_PCTX);
  ushort* hT    = (ushort*)(ws + OFF_HT);
  ushort* kvb   = (ushort*)(ws + OFF_KVB);

  constexpr int DSM2 = 4 * 8192 * 2;  // 65536 B (128^2 kernels)
  hipFuncSetAttribute((const void*)kv_gemm_bf16,
                      hipFuncAttributeMaxDynamicSharedMemorySize, DSM2);
  hipFuncSetAttribute((const void*)ctx_gemm_split,
                      hipFuncAttributeMaxDynamicSharedMemorySize, DSM2);
  hipFuncSetAttribute((const void*)final_gemm_bf16,
                      hipFuncAttributeMaxDynamicSharedMemorySize, DSM2);

  gn_stats1<<<dim3(8, 64), 256, 0, stream>>>(x, red);
  wconv2<<<768, 256, 0, stream>>>(qkv_w, proj_w, wkvb, pwb);
  wqt_kernel<<<dim3(16, 16), 256, 0, stream>>>(qkv_w, wqT);
  ht_kernel<<<dim3(64, 8, 8), 256, 0, stream>>>(x, red, gn_scale, gn_bias, hT);
  kv_gemm_bf16<<<dim3(32, 8, 8), 512, DSM2, stream>>>(wkvb, hT, qkv_b, kvb);
  zred<<<4096, 256, 0, stream>>>(kvb, invZ);
  ctx_gemm_split<<<dim3(4, 4, 64), 512, DSM2, stream>>>(kvb, pctx);
  ctx_red<<<1024, 256, 0, stream>>>(pctx, invZ, ctxb);
  m_gemm_bf16<<<dim3(8, 8, 8), 256, 0, stream>>>(pwb, ctxb, Mb);
  p_gemm_bf16<<<dim3(8, 8, 8), 256, 0, stream>>>(Mb, wqT, Pb);
  pb2_kernel<<<dim3(8, 8), 256, 0, stream>>>(Mb, qkv_b, proj_b, pb2);
  final_gemm_bf16<<<dim3(32, 4, 8), 512, DSM2, stream>>>(x, Pb, hT, pb2, out);
}

// Round 17
// 180.121 us; speedup vs baseline: 1.0518x; 1.0518x over previous
//
#include <hip/hip_runtime.h>

#define BB 8
#define CC 512
#define NT 4096
#define GG 8
#define CPG 64
#define EPSF 1e-6f
#define SQK 0.04419417382415922f  // 1/sqrt(512)

typedef __attribute__((ext_vector_type(8))) short bf16x8;
typedef __attribute__((ext_vector_type(4))) float f32x4;

// ws offsets (float units)
#define OFF_RED  0
#define OFF_PB2  4096
#define OFF_IZ   270336
#define OFF_WKV  274432
#define OFF_PWB  536576
#define OFF_WQT  667648
#define OFF_MB   798720
#define OFF_PBF  1847296
#define OFF_CTXB 2895872
#define OFF_PCTX 3944448
#define OFF_HT   12333056
#define OFF_KVB  20721664

__device__ __forceinline__ ushort f2bf(float f) {
  union { float f; uint u; } v; v.f = f;
  uint r = (v.u + 0x7fffu + ((v.u >> 16) & 1u)) >> 16;
  return (ushort)r;
}
__device__ __forceinline__ float bf2f(ushort h) {
  union { uint u; float f; } v; v.u = ((uint)h) << 16;
  return v.f;
}
__device__ __forceinline__ uint pk(float a, float b) {
  return (uint)f2bf(a) | ((uint)f2bf(b) << 16);
}
__device__ __forceinline__ void gload16(const ushort* g, ushort* l) {
  __builtin_amdgcn_global_load_lds((const __attribute__((address_space(1))) void*)g,
                                   (__attribute__((address_space(3))) void*)l, 16, 0, 0);
}
#define KSWZ(kofs, row) ((kofs) ^ ((((row) >> 1) & 3) << 3))

// XCD-aware bijective remap (m204): hardware block h -> logical tile l such
// that XCD k = h%8 owns the contiguous chunk [k*N/8, (k+1)*N/8). All grids
// here have N % 8 == 0. Pure renaming -> bit-identical results.
__device__ __forceinline__ void xcd_remap(int gx, int gy, int N,
                                          int& bx, int& by, int& bz) {
  int h = bx + gx * (by + gy * bz);
  int l = ((h & 7) * (N >> 3)) + (h >> 3);
  bx = l % gx;
  int t = l / gx;
  by = t % gy;
  bz = t / gy;
}

// ---------------- GN stats: partial sums (512 blocks) ----------------
__global__ __launch_bounds__(256) void gn_stats1(const float* __restrict__ x,
                                                 float* __restrict__ red) {
  int bg = blockIdx.y, chunk = blockIdx.x;
  const float4* p4 = (const float4*)(x + (size_t)bg * (CPG * NT) + (size_t)chunk * 32768);
  int tid = threadIdx.x;
  float s = 0.f, sq = 0.f;
  for (int i = tid; i < 8192; i += 256) {
    float4 v = p4[i];
    s  += v.x + v.y + v.z + v.w;
    sq += v.x * v.x + v.y * v.y + v.z * v.z + v.w * v.w;
  }
  for (int off = 32; off > 0; off >>= 1) {
    s  += __shfl_down(s, off);
    sq += __shfl_down(sq, off);
  }
  __shared__ float ls[4], lq[4];
  int wid = tid >> 6, lane = tid & 63;
  if (lane == 0) { ls[wid] = s; lq[wid] = sq; }
  __syncthreads();
  if (tid == 0) {
    red[(bg * 8 + chunk) * 2]     = ls[0] + ls[1] + ls[2] + ls[3];
    red[(bg * 8 + chunk) * 2 + 1] = lq[0] + lq[1] + lq[2] + lq[3];
  }
}

// ---------------- weight converts: kv rows (1024) + proj_w -> bf16 ---------
__global__ __launch_bounds__(256) void wconv2(const float* __restrict__ qkv_w,
                                              const float* __restrict__ proj_w,
                                              ushort* __restrict__ wkvb,
                                              ushort* __restrict__ pwb) {
  int bid = blockIdx.x;
  if (bid < 512) {
    int idx = (bid * 256 + threadIdx.x) * 4;
    float4 v = *(const float4*)(qkv_w + (size_t)CC * CC + idx);  // k+v rows
    *(uint2*)(wkvb + idx) = make_uint2(pk(v.x, v.y), pk(v.z, v.w));
  } else {
    int idx = ((bid - 512) * 256 + threadIdx.x) * 4;
    float4 v = *(const float4*)(proj_w + idx);
    *(uint2*)(pwb + idx) = make_uint2(pk(v.x, v.y), pk(v.z, v.w));
  }
}

// ---------------- Wq^T bf16: wqT[c][d] = qkv_w[d][c] (q rows) --------------
__global__ __launch_bounds__(256) void wqt_kernel(const float* __restrict__ qkv_w,
                                                  ushort* __restrict__ wqT) {
  __shared__ float t[32][33];
  int d0 = blockIdx.y * 32, c0 = blockIdx.x * 32;
  int tid = threadIdx.x;
  int r = tid >> 3, c4 = (tid & 7) * 4;
  float4 v = *(const float4*)(qkv_w + (size_t)(d0 + r) * CC + c0 + c4);
  t[r][c4] = v.x; t[r][c4 + 1] = v.y; t[r][c4 + 2] = v.z; t[r][c4 + 3] = v.w;
  __syncthreads();
  int r2 = tid >> 3, d4 = (tid & 7) * 4;
  uint w0 = pk(t[d4][r2], t[d4 + 1][r2]);
  uint w1 = pk(t[d4 + 2][r2], t[d4 + 3][r2]);
  *(uint2*)&wqT[(size_t)(c0 + r2) * CC + d0 + d4] = make_uint2(w0, w1);
}

// ---------------- h^T in bf16 (with inline GN finalize) --------------------
__global__ __launch_bounds__(256) void ht_kernel(
    const float* __restrict__ x, const float* __restrict__ red,
    const float* __restrict__ gn_scale, const float* __restrict__ gn_bias,
    ushort* __restrict__ hT) {
  __shared__ float ts[64][68];
  __shared__ float la[64], lb[64];
  int b = blockIdx.z, g = blockIdx.y, n0 = blockIdx.x * 64;
  int c0 = g * 64;
  int tid = threadIdx.x;
  if (tid == 0) {
    int bg = b * 8 + g;
    float s = 0.f, sq = 0.f;
#pragma unroll
    for (int i = 0; i < 8; i++) {
      s  += red[(bg * 8 + i) * 2];
      sq += red[(bg * 8 + i) * 2 + 1];
    }
    float mean = s / (float)(CPG * NT);
    float var  = sq / (float)(CPG * NT) - mean * mean;
    ts[0][0] = mean; ts[0][1] = rsqrtf(var + EPSF);
  }
  __syncthreads();
  if (tid < 64) {
    float mean = ts[0][0], rstd = ts[0][1];
    float a = gn_scale[c0 + tid] * rstd;
    la[tid] = a;
    lb[tid] = gn_bias[c0 + tid] - mean * a;
  }
  __syncthreads();
  int tn = (tid & 15) * 4, tc = tid >> 4;
#pragma unroll
  for (int it = 0; it < 4; it++) {
    int c = tc + it * 16;
    float a  = la[c];
    float bb = lb[c];
    float4 v = *(const float4*)(x + ((size_t)(b * CC + c0 + c)) * NT + n0 + tn);
    ts[c][tn]     = a * v.x + bb;
    ts[c][tn + 1] = a * v.y + bb;
    ts[c][tn + 2] = a * v.z + bb;
    ts[c][tn + 3] = a * v.w + bb;
  }
  __syncthreads();
#pragma unroll
  for (int it = 0; it < 2; it++) {
    int idx = tid + it * 256;
    int n = idx >> 3, c8 = (idx & 7) * 8;
    uint w[4];
#pragma unroll
    for (int j = 0; j < 4; j++)
      w[j] = pk(ts[c8 + 2 * j][n], ts[c8 + 2 * j + 1][n]);
    *(uint4*)&hT[((size_t)b * NT + n0 + n) * CC + c0 + c8] = make_uint4(w[0], w[1], w[2], w[3]);
  }
}

#define TBUF 16384  // ushorts per 256x64 buffer

// ===== coarse 256x256 loop: BK=64, 2-buf, 1-deep prefetch (R11-verified) ===
__device__ __forceinline__ void stage256(const ushort* __restrict__ G, ushort* L,
                                         int LD, int wave, int lane) {
  int rw = wave * 8 + (lane >> 3);
  int cg = lane & 7;
#pragma unroll
  for (int s = 0; s < 4; s++) {
    int row = s * 64 + rw;
    int gcol = (cg ^ (row & 7)) * 8;
    gload16(G + (size_t)row * LD + gcol, L + s * 4096 + wave * 512);
  }
}

template <int NTILES>
__device__ __forceinline__ void mfma256c(const ushort* __restrict__ A,
                                         const ushort* __restrict__ B,
                                         int LDA, int LDB, ushort* As, ushort* Bs,
                                         int tid, f32x4 acc[8][4]) {
  int wave = tid >> 6, lane = tid & 63;
  int wr = wave >> 2, wc = wave & 3;
  stage256(A, As, LDA, wave, lane);
  stage256(B, Bs, LDB, wave, lane);
  const ushort* gA = A + 64;
  const ushort* gB = B + 64;
  int rowA = wr * 128 + (lane & 15);
  int rowB = wc * 64 + (lane & 15);
  int kg0 = lane >> 4;
#pragma unroll 1
  for (int t = 0; t < NTILES; t++) {
    __builtin_amdgcn_s_barrier();
    asm volatile("" ::: "memory");
    if (t + 1 < NTILES) {
      stage256(gA, As + ((t + 1) & 1) * TBUF, LDA, wave, lane);
      stage256(gB, Bs + ((t + 1) & 1) * TBUF, LDB, wave, lane);
      gA += 64; gB += 64;
      asm volatile("s_waitcnt vmcnt(8)" ::: "memory");
    } else {
      asm volatile("s_waitcnt vmcnt(0)" ::: "memory");
    }
    __builtin_amdgcn_s_barrier();
    asm volatile("" ::: "memory");
    const ushort* Ab = As + (t & 1) * TBUF;
    const ushort* Bb = Bs + (t & 1) * TBUF;
#pragma unroll
    for (int kk = 0; kk < 2; kk++) {
      int kg = kg0 + kk * 4;
      bf16x8 bfr[4];
#pragma unroll
      for (int ni = 0; ni < 4; ni++) {
        int r = rowB + ni * 16;
        bfr[ni] = *(const bf16x8*)(Bb + r * 64 + ((kg ^ (r & 7)) << 3));
      }
#pragma unroll
      for (int mi = 0; mi < 8; mi++) {
        int r = rowA + mi * 16;
        bf16x8 afr = *(const bf16x8*)(Ab + r * 64 + ((kg ^ (r & 7)) << 3));
#pragma unroll
        for (int ni = 0; ni < 4; ni++)
          acc[mi][ni] = __builtin_amdgcn_mfma_f32_16x16x32_bf16(afr, bfr[ni], acc[mi][ni], 0, 0, 0);
      }
    }
  }
}

// ===== 128x128 loop: BK=64, 8 waves (2Mx4N, wave tile 64x32), 64KB LDS =====
__device__ __forceinline__ void stage128(const ushort* __restrict__ G, ushort* L,
                                         int LD, int tid) {
#pragma unroll
  for (int s = 0; s < 2; s++) {
    int row = s * 64 + (tid >> 3);
    int gcol = ((tid & 7) ^ (row & 7)) * 8;  // pre-swizzled global col
    gload16(G + (size_t)row * LD + gcol, L + s * 4096 + (tid >> 6) * 512);
  }
}

template <int NTILES>
__device__ __forceinline__ void mfma128(const ushort* __restrict__ A,
                                        const ushort* __restrict__ B,
                                        int LDA, int LDB, ushort* As, ushort* Bs,
                                        int tid, f32x4 acc[4][2]) {
  int wave = tid >> 6, lane = tid & 63;
  int wr = wave >> 2, wc = wave & 3;
  stage128(A, As, LDA, tid);
  stage128(B, Bs, LDB, tid);
  const ushort* gA = A + 64;
  const ushort* gB = B + 64;
  int rowA = wr * 64 + (lane & 15);
  int rowB = wc * 32 + (lane & 15);
  int kg0 = lane >> 4;
#pragma unroll 1
  for (int t = 0; t < NTILES; t++) {
    __builtin_amdgcn_s_barrier();
    asm volatile("" ::: "memory");
    if (t + 1 < NTILES) {
      stage128(gA, As + ((t + 1) & 1) * 8192, LDA, tid);
      stage128(gB, Bs + ((t + 1) & 1) * 8192, LDB, tid);
      gA += 64; gB += 64;
      asm volatile("s_waitcnt vmcnt(4)" ::: "memory");  // current tile landed
    } else {
      asm volatile("s_waitcnt vmcnt(0)" ::: "memory");
    }
    __builtin_amdgcn_s_barrier();
    asm volatile("" ::: "memory");
    const ushort* Ab = As + (t & 1) * 8192;
    const ushort* Bb = Bs + (t & 1) * 8192;
#pragma unroll
    for (int kk = 0; kk < 2; kk++) {
      int kg = kg0 + kk * 4;
      bf16x8 bfr[2];
#pragma unroll
      for (int ni = 0; ni < 2; ni++) {
        int r = rowB + ni * 16;
        bfr[ni] = *(const bf16x8*)(Bb + r * 64 + ((kg ^ (r & 7)) << 3));
      }
#pragma unroll
      for (int mi = 0; mi < 4; mi++) {
        int r = rowA + mi * 16;
        bf16x8 afr = *(const bf16x8*)(Ab + r * 64 + ((kg ^ (r & 7)) << 3));
#pragma unroll
        for (int ni = 0; ni < 2; ni++)
          acc[mi][ni] = __builtin_amdgcn_mfma_f32_16x16x32_bf16(afr, bfr[ni], acc[mi][ni], 0, 0, 0);
      }
    }
  }
}

// ------- 64x64 MFMA mainloop (m/p GEMMs), unchanged ------------------------
template <int KTOT, int LDA, int LDB>
__device__ __forceinline__ void mfma_loop64(const ushort* __restrict__ A,
                                            const ushort* __restrict__ B,
                                            ushort* As, ushort* Bs, int tid,
                                            f32x4 acc[2][2]) {
  int wave = tid >> 6, lane = tid & 63;
  int srow = tid >> 2;
  int kofs = KSWZ((tid & 3) * 8, srow & 15);
  const ushort* ga = A + (size_t)srow * LDA + kofs;
  const ushort* gb = B + (size_t)srow * LDB + kofs;
  int lo = wave * 512;
  int wm = (wave >> 1) * 32, wn = (wave & 1) * 32;
  int rowl = lane & 15;
  int kread = KSWZ((lane >> 4) * 8, rowl);
  int aoff = (wm + rowl) * 32 + kread;
  int boff = (wn + rowl) * 32 + kread;
  constexpr int NIT = KTOT / 32;
  gload16(ga, As + lo); gload16(gb, Bs + lo);
  ga += 32; gb += 32;
#pragma unroll 1
  for (int t = 0; t < NIT; t++) {
    int cb = (t & 1) * 2048;
    int nb = 2048 - cb;
    if (t + 1 < NIT) {
      gload16(ga, As + nb + lo); gload16(gb, Bs + nb + lo);
      ga += 32; gb += 32;
      asm volatile("s_waitcnt vmcnt(2)" ::: "memory");
    } else {
      asm volatile("s_waitcnt vmcnt(0)" ::: "memory");
    }
    __builtin_amdgcn_s_barrier();
    asm volatile("" ::: "memory");
    bf16x8 a[2], b[2];
#pragma unroll
    for (int m = 0; m < 2; m++) a[m] = *(const bf16x8*)(As + cb + aoff + m * 512);
#pragma unroll
    for (int n = 0; n < 2; n++) b[n] = *(const bf16x8*)(Bs + cb + boff + n * 512);
#pragma unroll
    for (int m = 0; m < 2; m++)
#pragma unroll
      for (int n = 0; n < 2; n++)
        acc[m][n] = __builtin_amdgcn_mfma_f32_16x16x32_bf16(a[m], b[n], acc[m][n], 0, 0, 0);
    asm volatile("" ::: "memory");
    __builtin_amdgcn_s_barrier();
    asm volatile("" ::: "memory");
  }
}

// --- kv GEMM bf16 (256^2, coarse, XCD-swizzled) + fused exp on k-rows ------
__global__ __launch_bounds__(512) void kv_gemm_bf16(
    const ushort* __restrict__ wkvb, const ushort* __restrict__ hT,
    const float* __restrict__ qkv_b, ushort* __restrict__ kvb) {
  extern __shared__ ushort lds[];
  ushort* As = lds;
  ushort* Bs = lds + 2 * TBUF;
  int bx = blockIdx.x, by = blockIdx.y, bz = blockIdx.z;
  xcd_remap(16, 4, 512, bx, by, bz);   // chunk=64 = one batch plane per XCD
  int b = bz, n0 = bx * 256, m0 = by * 256;
  int tid = threadIdx.x;
  f32x4 acc[8][4] = {{{0.f, 0.f, 0.f, 0.f}}};
  mfma256c<8>(wkvb + (size_t)m0 * CC, hT + (size_t)b * NT * CC + (size_t)n0 * CC,
              CC, CC, As, Bs, tid, acc);
  int wave = tid >> 6, lane = tid & 63;
  int wr = wave >> 2, wc = wave & 3;
  int col = lane & 15, rb = (lane >> 4) * 4;
  bool isK = (m0 < 512);
#pragma unroll
  for (int mi = 0; mi < 8; mi++)
#pragma unroll
    for (int j = 0; j < 4; j++) {
      int gm = m0 + wr * 128 + mi * 16 + rb + j;
      float bias = qkv_b[CC + gm];
      ushort* orow = kvb + ((size_t)(b * 1024 + gm)) * NT + n0 + wc * 64 + col;
#pragma unroll
      for (int ni = 0; ni < 4; ni++) {
        float val = acc[mi][ni][j] + bias;
        if (isK) val = __expf(val);  // softmax shift-invariant; |k|<~6
        orow[ni * 16] = f2bf(val);
      }
    }
}

// ---------------- invZ[b*512+d] = 1 / sum_n ek[d,n] (reads rounded ek) -----
__global__ __launch_bounds__(256) void zred(const ushort* __restrict__ kvb,
                                            float* __restrict__ invZ) {
  int row = blockIdx.x;  // b*512 + d
  int b = row >> 9, d = row & 511;
  const ushort* p = kvb + ((size_t)(b * 1024 + d)) * NT;
  int tid = threadIdx.x;
  uint4 r0 = *(const uint4*)(p + tid * 16);
  uint4 r1 = *(const uint4*)(p + tid * 16 + 8);
  uint w[8] = {r0.x, r0.y, r0.z, r0.w, r1.x, r1.y, r1.z, r1.w};
  float s = 0.f;
#pragma unroll
  for (int i = 0; i < 8; i++) {
    union { uint u; float f; } lo, hi;
    lo.u = w[i] << 16; hi.u = w[i] & 0xffff0000u;
    s += lo.f + hi.f;
  }
  for (int off = 32; off > 0; off >>= 1) s += __shfl_down(s, off);
  __shared__ float red[4];
  int wid = tid >> 6, lane = tid & 63;
  if (lane == 0) red[wid] = s;
  __syncthreads();
  if (tid == 0) invZ[row] = 1.f / (red[0] + red[1] + red[2] + red[3]);
}

// --- ctx split-K (256^2, coarse, XCD-swizzled): pctx = sum_{n in s} ek v ---
__global__ __launch_bounds__(512) void ctx_gemm_split(
    const ushort* __restrict__ kvb, ushort* __restrict__ pctx) {
  extern __shared__ ushort lds[];
  ushort* As = lds;
  ushort* Bs = lds + 2 * TBUF;
  int bx = blockIdx.x, by = blockIdx.y, bz = blockIdx.z;
  xcd_remap(2, 2, 256, bx, by, bz);    // chunk=32 = 8 (b,s) slices per XCD
  int e0 = bx * 256, d0 = by * 256;
  int b = bz >> 3, s = bz & 7;
  int tid = threadIdx.x;
  f32x4 acc[8][4] = {{{0.f, 0.f, 0.f, 0.f}}};
  const ushort* K = kvb + (size_t)b * 1024 * NT + (size_t)d0 * NT + s * 512;
  const ushort* V = kvb + ((size_t)b * 1024 + 512) * NT + (size_t)e0 * NT + s * 512;
  mfma256c<8>(K, V, NT, NT, As, Bs, tid, acc);
  int wave = tid >> 6, lane = tid & 63;
  int wr = wave >> 2, wc = wave & 3;
  int col = lane & 15, rb = (lane >> 4) * 4;
#pragma unroll
  for (int mi = 0; mi < 8; mi++)
#pragma unroll
    for (int j = 0; j < 4; j++) {
      int gd = d0 + wr * 128 + mi * 16 + rb + j;
      ushort* orow = pctx + ((size_t)(b * 8 + s) * CC + gd) * CC + e0 + wc * 64 + col;
#pragma unroll
      for (int ni = 0; ni < 4; ni++)
        orow[ni * 16] = f2bf(acc[mi][ni][j]);
    }
}

// ---------------- reduce splits + row-normalize -> bf16 ctx ----------------
__global__ __launch_bounds__(256) void ctx_red(const ushort* __restrict__ pctx,
                                               const float* __restrict__ invZ,
                                               ushort* __restrict__ ctxb) {
  int t = blockIdx.x * 256 + threadIdx.x;
  int b = t >> 15;
  int r = (t & 32767) * 8;
  int d = r >> 9;
  float iz = invZ[b * 512 + d];
  const ushort* base = pctx + (size_t)b * 8 * 262144 + r;
  float f[8] = {};
#pragma unroll
  for (int s = 0; s < 8; s++) {
    uint4 v = *(const uint4*)(base + (size_t)s * 262144);
    uint w[4] = {v.x, v.y, v.z, v.w};
#pragma unroll
    for (int j = 0; j < 4; j++) {
      union { uint u; float f; } lo, hi;
      lo.u = w[j] << 16; hi.u = w[j] & 0xffff0000u;
      f[2 * j] += lo.f; f[2 * j + 1] += hi.f;
    }
  }
  uint o[4];
#pragma unroll
  for (int j = 0; j < 4; j++) o[j] = pk(f[2 * j] * iz, f[2 * j + 1] * iz);
  *(uint4*)(ctxb + (size_t)b * 262144 + r) = make_uint4(o[0], o[1], o[2], o[3]);
}

// ---------------- M GEMM: Mb[b,o,d] = SQK * sum_e pw[o,e] ctx[b,d,e] -------
__global__ __launch_bounds__(256) void m_gemm_bf16(
    const ushort* __restrict__ pwb, const ushort* __restrict__ ctxb,
    ushort* __restrict__ Mb) {
  __shared__ ushort As[4096], Bs[4096];
  int b = blockIdx.z, d0 = blockIdx.x * 64, o0 = blockIdx.y * 64;
  int tid = threadIdx.x;
  f32x4 acc[2][2] = {{{0.f, 0.f, 0.f, 0.f}}};
  mfma_loop64<CC, CC, CC>(pwb + (size_t)o0 * CC,
                          ctxb + (size_t)b * CC * CC + (size_t)d0 * CC, As, Bs, tid, acc);
  int wave = tid >> 6, lane = tid & 63;
  int wm = (wave >> 1) * 32, wn = (wave & 1) * 32;
  int col = lane & 15, rb = (lane >> 4) * 4;
#pragma unroll
  for (int m = 0; m < 2; m++)
#pragma unroll
    for (int n = 0; n < 2; n++)
#pragma unroll
      for (int j = 0; j < 4; j++) {
        int go = o0 + wm + m * 16 + rb + j;
        int gd = d0 + wn + n * 16 + col;
        Mb[((size_t)b * CC + go) * CC + gd] = f2bf(acc[m][n][j] * SQK);
      }
}

// ---------------- P GEMM: Pb[b,o,c] = sum_d Mb[b,o,d] wqT[c,d] -------------
__global__ __launch_bounds__(256) void p_gemm_bf16(
    const ushort* __restrict__ Mb, const ushort* __restrict__ wqT,
    ushort* __restrict__ Pb) {
  __shared__ ushort As[4096], Bs[4096];
  int b = blockIdx.z, c0 = blockIdx.x * 64, o0 = blockIdx.y * 64;
  int tid = threadIdx.x;
  f32x4 acc[2][2] = {{{0.f, 0.f, 0.f, 0.f}}};
  mfma_loop64<CC, CC, CC>(Mb + (size_t)b * CC * CC + (size_t)o0 * CC,
                          wqT + (size_t)c0 * CC, As, Bs, tid, acc);
  int wave = tid >> 6, lane = tid & 63;
  int wm = (wave >> 1) * 32, wn = (wave & 1) * 32;
  int col = lane & 15, rb = (lane >> 4) * 4;
#pragma unroll
  for (int m = 0; m < 2; m++)
#pragma unroll
    for (int n = 0; n < 2; n++)
#pragma unroll
      for (int j = 0; j < 4; j++) {
        int go = o0 + wm + m * 16 + rb + j;
        int gc = c0 + wn + n * 16 + col;
        Pb[((size_t)b * CC + go) * CC + gc] = f2bf(acc[m][n][j]);
      }
}

// ---------------- pb2[b,o] = sum_d Mb[b,o,d]*bq[d] + proj_b[o] -------------
__global__ __launch_bounds__(256) void pb2_kernel(
    const ushort* __restrict__ Mb, const float* __restrict__ qkv_b,
    const float* __restrict__ proj_b, float* __restrict__ pb2) {
  int b = blockIdx.x, og = blockIdx.y;
  int r = og * 64 + (threadIdx.x >> 2);
  int q = threadIdx.x & 3;
  const ushort* Mr = Mb + ((size_t)(b * CC + r)) * CC + q * 128;
  const float* bq = qkv_b + q * 128;
  float s = 0.f;
#pragma unroll
  for (int i = 0; i < 16; i++) {
    uint4 v = *(const uint4*)(Mr + i * 8);
    uint w[4] = {v.x, v.y, v.z, v.w};
#pragma unroll
    for (int j = 0; j < 4; j++) {
      union { uint u; float f; } lo, hi;
      lo.u = w[j] << 16; hi.u = w[j] & 0xffff0000u;
      s += lo.f * bq[i * 8 + 2 * j] + hi.f * bq[i * 8 + 2 * j + 1];
    }
  }
  s += __shfl_xor(s, 1);
  s += __shfl_xor(s, 2);
  if (q == 0) pb2[b * CC + r] = s + proj_b[r];
}

// --- final GEMM (128^2, 8-wave, 2 blocks/CU, XCD-swizzled) -----------------
__global__ __launch_bounds__(512) void final_gemm_bf16(
    const float* __restrict__ x, const ushort* __restrict__ Pb,
    const ushort* __restrict__ hT, const float* __restrict__ pb2,
    float* __restrict__ out) {
  extern __shared__ ushort lds[];
  ushort* As = lds;
  ushort* Bs = lds + 2 * 8192;
  int bx = blockIdx.x, by = blockIdx.y, bz = blockIdx.z;
  xcd_remap(32, 4, 1024, bx, by, bz);  // chunk=128 = one batch plane per XCD
  int b = bz, n0 = bx * 128, m0 = by * 128;
  int tid = threadIdx.x;
  f32x4 acc[4][2] = {{{0.f, 0.f, 0.f, 0.f}}};
  mfma128<8>(Pb + (size_t)b * CC * CC + (size_t)m0 * CC,
             hT + (size_t)b * NT * CC + (size_t)n0 * CC, CC, CC, As, Bs, tid, acc);
  int wave = tid >> 6, lane = tid & 63;
  int wr = wave >> 2, wc = wave & 3;
  int col = lane & 15, rb = (lane >> 4) * 4;
#pragma unroll
  for (int mi = 0; mi < 4; mi++)
#pragma unroll
    for (int j = 0; j < 4; j++) {
      int gm = m0 + wr * 64 + mi * 16 + rb + j;
      float bias = pb2[b * CC + gm];
      size_t rowoff = ((size_t)(b * CC + gm)) * NT + n0 + wc * 32 + col;
#pragma unroll
      for (int ni = 0; ni < 2; ni++)
        out[rowoff + ni * 16] = acc[mi][ni][j] + bias + x[rowoff + ni * 16];
    }
}

extern "C" void kernel_launch(void* const* d_in, const int* in_sizes, int n_in,
                              void* d_out, int out_size, void* d_ws, size_t ws_size,
                              hipStream_t stream) {
  const float* x        = (const float*)d_in[0];
  const float* qkv_w    = (const float*)d_in[1];
  const float* qkv_b    = (const float*)d_in[2];
  const float* proj_w   = (const float*)d_in[3];
  const float* proj_b   = (const float*)d_in[4];
  const float* gn_scale = (const float*)d_in[5];
  const float* gn_bias  = (const float*)d_in[6];
  float* out = (float*)d_out;
  float* ws  = (float*)d_ws;

  float*  red   = ws + OFF_RED;
  float*  pb2   = ws + OFF_PB2;
  float*  invZ  = ws + OFF_IZ;
  ushort* wkvb  = (ushort*)(ws + OFF_WKV);
  ushort* pwb   = (ushort*)(ws + OFF_PWB);
  ushort* wqT   = (ushort*)(ws + OFF_WQT);
  ushort* Mb    = (ushort*)(ws + OFF_MB);
  ushort* Pb    = (ushort*)(ws + OFF_PBF);
  ushort* ctxb  = (ushort*)(ws + OFF_CTXB);
  ushort* pctx  = (ushort*)(ws + OFF_PCTX);
  ushort* hT    = (ushort*)(ws + OFF_HT);
  ushort* kvb   = (ushort*)(ws + OFF_KVB);

  constexpr int DSM  = 4 * TBUF * 2;  // 131072 B (256^2 kernels)
  constexpr int DSM2 = 4 * 8192 * 2;  // 65536 B  (128^2 final)
  hipFuncSetAttribute((const void*)kv_gemm_bf16,
                      hipFuncAttributeMaxDynamicSharedMemorySize, DSM);
  hipFuncSetAttribute((const void*)ctx_gemm_split,
                      hipFuncAttributeMaxDynamicSharedMemorySize, DSM);
  hipFuncSetAttribute((const void*)final_gemm_bf16,
                      hipFuncAttributeMaxDynamicSharedMemorySize, DSM2);

  gn_stats1<<<dim3(8, 64), 256, 0, stream>>>(x, red);
  wconv2<<<768, 256, 0, stream>>>(qkv_w, proj_w, wkvb, pwb);
  wqt_kernel<<<dim3(16, 16), 256, 0, stream>>>(qkv_w, wqT);
  ht_kernel<<<dim3(64, 8, 8), 256, 0, stream>>>(x, red, gn_scale, gn_bias, hT);
  kv_gemm_bf16<<<dim3(16, 4, 8), 512, DSM, stream>>>(wkvb, hT, qkv_b, kvb);
  zred<<<4096, 256, 0, stream>>>(kvb, invZ);
  ctx_gemm_split<<<dim3(2, 2, 64), 512, DSM, stream>>>(kvb, pctx);
  ctx_red<<<1024, 256, 0, stream>>>(pctx, invZ, ctxb);
  m_gemm_bf16<<<dim3(8, 8, 8), 256, 0, stream>>>(pwb, ctxb, Mb);
  p_gemm_bf16<<<dim3(8, 8, 8), 256, 0, stream>>>(Mb, wqT, Pb);
  pb2_kernel<<<dim3(8, 8), 256, 0, stream>>>(Mb, qkv_b, proj_b, pb2);
  final_gemm_bf16<<<dim3(32, 4, 8), 512, DSM2, stream>>>(x, Pb, hT, pb2, out);
}

// Round 18
// 178.930 us; speedup vs baseline: 1.0588x; 1.0067x over previous
//
#include <hip/hip_runtime.h>

#define BB 8
#define CC 512
#define NT 4096
#define GG 8
#define CPG 64
#define EPSF 1e-6f
#define SQK 0.04419417382415922f  // 1/sqrt(512)

typedef __attribute__((ext_vector_type(8))) short bf16x8;
typedef __attribute__((ext_vector_type(4))) float f32x4;

// ws offsets (float units)
#define OFF_RED  0
#define OFF_PB2  4096
#define OFF_IZ   270336
#define OFF_WKV  274432
#define OFF_PWB  536576
#define OFF_WQT  667648
#define OFF_MB   798720
#define OFF_PBF  1847296
#define OFF_CTXB 2895872
#define OFF_PCTX 3944448
#define OFF_HT   12333056
#define OFF_KVB  20721664

__device__ __forceinline__ ushort f2bf(float f) {
  union { float f; uint u; } v; v.f = f;
  uint r = (v.u + 0x7fffu + ((v.u >> 16) & 1u)) >> 16;
  return (ushort)r;
}
__device__ __forceinline__ float bf2f(ushort h) {
  union { uint u; float f; } v; v.u = ((uint)h) << 16;
  return v.f;
}
__device__ __forceinline__ uint pk(float a, float b) {
  return (uint)f2bf(a) | ((uint)f2bf(b) << 16);
}
__device__ __forceinline__ void gload16(const ushort* g, ushort* l) {
  __builtin_amdgcn_global_load_lds((const __attribute__((address_space(1))) void*)g,
                                   (__attribute__((address_space(3))) void*)l, 16, 0, 0);
}
#define KSWZ(kofs, row) ((kofs) ^ ((((row) >> 1) & 3) << 3))

// XCD-aware bijective remap (m204): hardware block h -> logical tile l such
// that XCD k = h%8 owns the contiguous chunk [k*N/8, (k+1)*N/8). All grids
// here have N % 8 == 0. Pure renaming -> bit-identical results.
__device__ __forceinline__ void xcd_remap(int gx, int gy, int N,
                                          int& bx, int& by, int& bz) {
  int h = bx + gx * (by + gy * bz);
  int l = ((h & 7) * (N >> 3)) + (h >> 3);
  bx = l % gx;
  int t = l / gx;
  by = t % gy;
  bz = t / gy;
}

// ---- fused prep: GN partial stats + weight converts + Wq^T (1536 blocks) --
__global__ __launch_bounds__(256) void prep_kernel(
    const float* __restrict__ x, const float* __restrict__ qkv_w,
    const float* __restrict__ proj_w, float* __restrict__ red,
    ushort* __restrict__ wkvb, ushort* __restrict__ pwb,
    ushort* __restrict__ wqT) {
  int bid = blockIdx.x;
  int tid = threadIdx.x;
  if (bid < 512) {
    // GN partial sums: bg = bid>>3, chunk = bid&7
    int bg = bid >> 3, chunk = bid & 7;
    const float4* p4 = (const float4*)(x + (size_t)bg * (CPG * NT) + (size_t)chunk * 32768);
    float s = 0.f, sq = 0.f;
    for (int i = tid; i < 8192; i += 256) {
      float4 v = p4[i];
      s  += v.x + v.y + v.z + v.w;
      sq += v.x * v.x + v.y * v.y + v.z * v.z + v.w * v.w;
    }
    for (int off = 32; off > 0; off >>= 1) {
      s  += __shfl_down(s, off);
      sq += __shfl_down(sq, off);
    }
    __shared__ float ls[4], lq[4];
    int wid = tid >> 6, lane = tid & 63;
    if (lane == 0) { ls[wid] = s; lq[wid] = sq; }
    __syncthreads();
    if (tid == 0) {
      red[(bg * 8 + chunk) * 2]     = ls[0] + ls[1] + ls[2] + ls[3];
      red[(bg * 8 + chunk) * 2 + 1] = lq[0] + lq[1] + lq[2] + lq[3];
    }
  } else if (bid < 1024) {
    // kv weight rows -> bf16
    int idx = ((bid - 512) * 256 + tid) * 4;
    float4 v = *(const float4*)(qkv_w + (size_t)CC * CC + idx);
    *(uint2*)(wkvb + idx) = make_uint2(pk(v.x, v.y), pk(v.z, v.w));
  } else if (bid < 1280) {
    // proj_w -> bf16
    int idx = ((bid - 1024) * 256 + tid) * 4;
    float4 v = *(const float4*)(proj_w + idx);
    *(uint2*)(pwb + idx) = make_uint2(pk(v.x, v.y), pk(v.z, v.w));
  } else {
    // Wq^T tiles: t in [0,256): c0 = (t&15)*32, d0 = (t>>4)*32
    __shared__ float t[32][33];
    int tt = bid - 1280;
    int c0 = (tt & 15) * 32, d0 = (tt >> 4) * 32;
    int r = tid >> 3, c4 = (tid & 7) * 4;
    float4 v = *(const float4*)(qkv_w + (size_t)(d0 + r) * CC + c0 + c4);
    t[r][c4] = v.x; t[r][c4 + 1] = v.y; t[r][c4 + 2] = v.z; t[r][c4 + 3] = v.w;
    __syncthreads();
    int r2 = tid >> 3, d4 = (tid & 7) * 4;
    uint w0 = pk(t[d4][r2], t[d4 + 1][r2]);
    uint w1 = pk(t[d4 + 2][r2], t[d4 + 3][r2]);
    *(uint2*)&wqT[(size_t)(c0 + r2) * CC + d0 + d4] = make_uint2(w0, w1);
  }
}

// ---------------- h^T in bf16 (with inline GN finalize) --------------------
__global__ __launch_bounds__(256) void ht_kernel(
    const float* __restrict__ x, const float* __restrict__ red,
    const float* __restrict__ gn_scale, const float* __restrict__ gn_bias,
    ushort* __restrict__ hT) {
  __shared__ float ts[64][68];
  __shared__ float la[64], lb[64];
  int b = blockIdx.z, g = blockIdx.y, n0 = blockIdx.x * 64;
  int c0 = g * 64;
  int tid = threadIdx.x;
  if (tid == 0) {
    int bg = b * 8 + g;
    float s = 0.f, sq = 0.f;
#pragma unroll
    for (int i = 0; i < 8; i++) {
      s  += red[(bg * 8 + i) * 2];
      sq += red[(bg * 8 + i) * 2 + 1];
    }
    float mean = s / (float)(CPG * NT);
    float var  = sq / (float)(CPG * NT) - mean * mean;
    ts[0][0] = mean; ts[0][1] = rsqrtf(var + EPSF);
  }
  __syncthreads();
  if (tid < 64) {
    float mean = ts[0][0], rstd = ts[0][1];
    float a = gn_scale[c0 + tid] * rstd;
    la[tid] = a;
    lb[tid] = gn_bias[c0 + tid] - mean * a;
  }
  __syncthreads();
  int tn = (tid & 15) * 4, tc = tid >> 4;
#pragma unroll
  for (int it = 0; it < 4; it++) {
    int c = tc + it * 16;
    float a  = la[c];
    float bb = lb[c];
    float4 v = *(const float4*)(x + ((size_t)(b * CC + c0 + c)) * NT + n0 + tn);
    ts[c][tn]     = a * v.x + bb;
    ts[c][tn + 1] = a * v.y + bb;
    ts[c][tn + 2] = a * v.z + bb;
    ts[c][tn + 3] = a * v.w + bb;
  }
  __syncthreads();
#pragma unroll
  for (int it = 0; it < 2; it++) {
    int idx = tid + it * 256;
    int n = idx >> 3, c8 = (idx & 7) * 8;
    uint w[4];
#pragma unroll
    for (int j = 0; j < 4; j++)
      w[j] = pk(ts[c8 + 2 * j][n], ts[c8 + 2 * j + 1][n]);
    *(uint4*)&hT[((size_t)b * NT + n0 + n) * CC + c0 + c8] = make_uint4(w[0], w[1], w[2], w[3]);
  }
}

#define TBUF 16384  // ushorts per 256x64 buffer

// ===== coarse 256x256 loop: BK=64, 2-buf, 1-deep prefetch (R11-verified) ===
__device__ __forceinline__ void stage256(const ushort* __restrict__ G, ushort* L,
                                         int LD, int wave, int lane) {
  int rw = wave * 8 + (lane >> 3);
  int cg = lane & 7;
#pragma unroll
  for (int s = 0; s < 4; s++) {
    int row = s * 64 + rw;
    int gcol = (cg ^ (row & 7)) * 8;
    gload16(G + (size_t)row * LD + gcol, L + s * 4096 + wave * 512);
  }
}

template <int NTILES>
__device__ __forceinline__ void mfma256c(const ushort* __restrict__ A,
                                         const ushort* __restrict__ B,
                                         int LDA, int LDB, ushort* As, ushort* Bs,
                                         int tid, f32x4 acc[8][4]) {
  int wave = tid >> 6, lane = tid & 63;
  int wr = wave >> 2, wc = wave & 3;
  stage256(A, As, LDA, wave, lane);
  stage256(B, Bs, LDB, wave, lane);
  const ushort* gA = A + 64;
  const ushort* gB = B + 64;
  int rowA = wr * 128 + (lane & 15);
  int rowB = wc * 64 + (lane & 15);
  int kg0 = lane >> 4;
#pragma unroll 1
  for (int t = 0; t < NTILES; t++) {
    __builtin_amdgcn_s_barrier();
    asm volatile("" ::: "memory");
    if (t + 1 < NTILES) {
      stage256(gA, As + ((t + 1) & 1) * TBUF, LDA, wave, lane);
      stage256(gB, Bs + ((t + 1) & 1) * TBUF, LDB, wave, lane);
      gA += 64; gB += 64;
      asm volatile("s_waitcnt vmcnt(8)" ::: "memory");
    } else {
      asm volatile("s_waitcnt vmcnt(0)" ::: "memory");
    }
    __builtin_amdgcn_s_barrier();
    asm volatile("" ::: "memory");
    const ushort* Ab = As + (t & 1) * TBUF;
    const ushort* Bb = Bs + (t & 1) * TBUF;
#pragma unroll
    for (int kk = 0; kk < 2; kk++) {
      int kg = kg0 + kk * 4;
      bf16x8 bfr[4];
#pragma unroll
      for (int ni = 0; ni < 4; ni++) {
        int r = rowB + ni * 16;
        bfr[ni] = *(const bf16x8*)(Bb + r * 64 + ((kg ^ (r & 7)) << 3));
      }
#pragma unroll
      for (int mi = 0; mi < 8; mi++) {
        int r = rowA + mi * 16;
        bf16x8 afr = *(const bf16x8*)(Ab + r * 64 + ((kg ^ (r & 7)) << 3));
#pragma unroll
        for (int ni = 0; ni < 4; ni++)
          acc[mi][ni] = __builtin_amdgcn_mfma_f32_16x16x32_bf16(afr, bfr[ni], acc[mi][ni], 0, 0, 0);
      }
    }
  }
}

// ===== 128x128 loop: BK=64, 8 waves (2Mx4N, wave tile 64x32), 64KB LDS =====
__device__ __forceinline__ void stage128(const ushort* __restrict__ G, ushort* L,
                                         int LD, int tid) {
#pragma unroll
  for (int s = 0; s < 2; s++) {
    int row = s * 64 + (tid >> 3);
    int gcol = ((tid & 7) ^ (row & 7)) * 8;  // pre-swizzled global col
    gload16(G + (size_t)row * LD + gcol, L + s * 4096 + (tid >> 6) * 512);
  }
}

template <int NTILES>
__device__ __forceinline__ void mfma128(const ushort* __restrict__ A,
                                        const ushort* __restrict__ B,
                                        int LDA, int LDB, ushort* As, ushort* Bs,
                                        int tid, f32x4 acc[4][2]) {
  int wave = tid >> 6, lane = tid & 63;
  int wr = wave >> 2, wc = wave & 3;
  stage128(A, As, LDA, tid);
  stage128(B, Bs, LDB, tid);
  const ushort* gA = A + 64;
  const ushort* gB = B + 64;
  int rowA = wr * 64 + (lane & 15);
  int rowB = wc * 32 + (lane & 15);
  int kg0 = lane >> 4;
#pragma unroll 1
  for (int t = 0; t < NTILES; t++) {
    __builtin_amdgcn_s_barrier();
    asm volatile("" ::: "memory");
    if (t + 1 < NTILES) {
      stage128(gA, As + ((t + 1) & 1) * 8192, LDA, tid);
      stage128(gB, Bs + ((t + 1) & 1) * 8192, LDB, tid);
      gA += 64; gB += 64;
      asm volatile("s_waitcnt vmcnt(4)" ::: "memory");  // current tile landed
    } else {
      asm volatile("s_waitcnt vmcnt(0)" ::: "memory");
    }
    __builtin_amdgcn_s_barrier();
    asm volatile("" ::: "memory");
    const ushort* Ab = As + (t & 1) * 8192;
    const ushort* Bb = Bs + (t & 1) * 8192;
#pragma unroll
    for (int kk = 0; kk < 2; kk++) {
      int kg = kg0 + kk * 4;
      bf16x8 bfr[2];
#pragma unroll
      for (int ni = 0; ni < 2; ni++) {
        int r = rowB + ni * 16;
        bfr[ni] = *(const bf16x8*)(Bb + r * 64 + ((kg ^ (r & 7)) << 3));
      }
#pragma unroll
      for (int mi = 0; mi < 4; mi++) {
        int r = rowA + mi * 16;
        bf16x8 afr = *(const bf16x8*)(Ab + r * 64 + ((kg ^ (r & 7)) << 3));
#pragma unroll
        for (int ni = 0; ni < 2; ni++)
          acc[mi][ni] = __builtin_amdgcn_mfma_f32_16x16x32_bf16(afr, bfr[ni], acc[mi][ni], 0, 0, 0);
      }
    }
  }
}

// ------- 64x64 MFMA mainloop (m/p GEMMs), unchanged ------------------------
template <int KTOT, int LDA, int LDB>
__device__ __forceinline__ void mfma_loop64(const ushort* __restrict__ A,
                                            const ushort* __restrict__ B,
                                            ushort* As, ushort* Bs, int tid,
                                            f32x4 acc[2][2]) {
  int wave = tid >> 6, lane = tid & 63;
  int srow = tid >> 2;
  int kofs = KSWZ((tid & 3) * 8, srow & 15);
  const ushort* ga = A + (size_t)srow * LDA + kofs;
  const ushort* gb = B + (size_t)srow * LDB + kofs;
  int lo = wave * 512;
  int wm = (wave >> 1) * 32, wn = (wave & 1) * 32;
  int rowl = lane & 15;
  int kread = KSWZ((lane >> 4) * 8, rowl);
  int aoff = (wm + rowl) * 32 + kread;
  int boff = (wn + rowl) * 32 + kread;
  constexpr int NIT = KTOT / 32;
  gload16(ga, As + lo); gload16(gb, Bs + lo);
  ga += 32; gb += 32;
#pragma unroll 1
  for (int t = 0; t < NIT; t++) {
    int cb = (t & 1) * 2048;
    int nb = 2048 - cb;
    if (t + 1 < NIT) {
      gload16(ga, As + nb + lo); gload16(gb, Bs + nb + lo);
      ga += 32; gb += 32;
      asm volatile("s_waitcnt vmcnt(2)" ::: "memory");
    } else {
      asm volatile("s_waitcnt vmcnt(0)" ::: "memory");
    }
    __builtin_amdgcn_s_barrier();
    asm volatile("" ::: "memory");
    bf16x8 a[2], b[2];
#pragma unroll
    for (int m = 0; m < 2; m++) a[m] = *(const bf16x8*)(As + cb + aoff + m * 512);
#pragma unroll
    for (int n = 0; n < 2; n++) b[n] = *(const bf16x8*)(Bs + cb + boff + n * 512);
#pragma unroll
    for (int m = 0; m < 2; m++)
#pragma unroll
      for (int n = 0; n < 2; n++)
        acc[m][n] = __builtin_amdgcn_mfma_f32_16x16x32_bf16(a[m], b[n], acc[m][n], 0, 0, 0);
    asm volatile("" ::: "memory");
    __builtin_amdgcn_s_barrier();
    asm volatile("" ::: "memory");
  }
}

// --- kv GEMM bf16 (256^2, coarse, XCD-swizzled) + fused exp on k-rows ------
__global__ __launch_bounds__(512) void kv_gemm_bf16(
    const ushort* __restrict__ wkvb, const ushort* __restrict__ hT,
    const float* __restrict__ qkv_b, ushort* __restrict__ kvb) {
  extern __shared__ ushort lds[];
  ushort* As = lds;
  ushort* Bs = lds + 2 * TBUF;
  int bx = blockIdx.x, by = blockIdx.y, bz = blockIdx.z;
  xcd_remap(16, 4, 512, bx, by, bz);   // chunk=64 = one batch plane per XCD
  int b = bz, n0 = bx * 256, m0 = by * 256;
  int tid = threadIdx.x;
  f32x4 acc[8][4] = {{{0.f, 0.f, 0.f, 0.f}}};
  mfma256c<8>(wkvb + (size_t)m0 * CC, hT + (size_t)b * NT * CC + (size_t)n0 * CC,
              CC, CC, As, Bs, tid, acc);
  int wave = tid >> 6, lane = tid & 63;
  int wr = wave >> 2, wc = wave & 3;
  int col = lane & 15, rb = (lane >> 4) * 4;
  bool isK = (m0 < 512);
#pragma unroll
  for (int mi = 0; mi < 8; mi++)
#pragma unroll
    for (int j = 0; j < 4; j++) {
      int gm = m0 + wr * 128 + mi * 16 + rb + j;
      float bias = qkv_b[CC + gm];
      ushort* orow = kvb + ((size_t)(b * 1024 + gm)) * NT + n0 + wc * 64 + col;
#pragma unroll
      for (int ni = 0; ni < 4; ni++) {
        float val = acc[mi][ni][j] + bias;
        if (isK) val = __expf(val);  // softmax shift-invariant; |k|<~6
        orow[ni * 16] = f2bf(val);
      }
    }
}

// ---------------- invZ[b*512+d] = 1 / sum_n ek[d,n] (reads rounded ek) -----
__global__ __launch_bounds__(256) void zred(const ushort* __restrict__ kvb,
                                            float* __restrict__ invZ) {
  int row = blockIdx.x;  // b*512 + d
  int b = row >> 9, d = row & 511;
  const ushort* p = kvb + ((size_t)(b * 1024 + d)) * NT;
  int tid = threadIdx.x;
  uint4 r0 = *(const uint4*)(p + tid * 16);
  uint4 r1 = *(const uint4*)(p + tid * 16 + 8);
  uint w[8] = {r0.x, r0.y, r0.z, r0.w, r1.x, r1.y, r1.z, r1.w};
  float s = 0.f;
#pragma unroll
  for (int i = 0; i < 8; i++) {
    union { uint u; float f; } lo, hi;
    lo.u = w[i] << 16; hi.u = w[i] & 0xffff0000u;
    s += lo.f + hi.f;
  }
  for (int off = 32; off > 0; off >>= 1) s += __shfl_down(s, off);
  __shared__ float red[4];
  int wid = tid >> 6, lane = tid & 63;
  if (lane == 0) red[wid] = s;
  __syncthreads();
  if (tid == 0) invZ[row] = 1.f / (red[0] + red[1] + red[2] + red[3]);
}

// --- ctx split-K (256^2, coarse, XCD-swizzled): pctx = sum_{n in s} ek v ---
__global__ __launch_bounds__(512) void ctx_gemm_split(
    const ushort* __restrict__ kvb, ushort* __restrict__ pctx) {
  extern __shared__ ushort lds[];
  ushort* As = lds;
  ushort* Bs = lds + 2 * TBUF;
  int bx = blockIdx.x, by = blockIdx.y, bz = blockIdx.z;
  xcd_remap(2, 2, 256, bx, by, bz);    // chunk=32 = 8 (b,s) slices per XCD
  int e0 = bx * 256, d0 = by * 256;
  int b = bz >> 3, s = bz & 7;
  int tid = threadIdx.x;
  f32x4 acc[8][4] = {{{0.f, 0.f, 0.f, 0.f}}};
  const ushort* K = kvb + (size_t)b * 1024 * NT + (size_t)d0 * NT + s * 512;
  const ushort* V = kvb + ((size_t)b * 1024 + 512) * NT + (size_t)e0 * NT + s * 512;
  mfma256c<8>(K, V, NT, NT, As, Bs, tid, acc);
  int wave = tid >> 6, lane = tid & 63;
  int wr = wave >> 2, wc = wave & 3;
  int col = lane & 15, rb = (lane >> 4) * 4;
#pragma unroll
  for (int mi = 0; mi < 8; mi++)
#pragma unroll
    for (int j = 0; j < 4; j++) {
      int gd = d0 + wr * 128 + mi * 16 + rb + j;
      ushort* orow = pctx + ((size_t)(b * 8 + s) * CC + gd) * CC + e0 + wc * 64 + col;
#pragma unroll
      for (int ni = 0; ni < 4; ni++)
        orow[ni * 16] = f2bf(acc[mi][ni][j]);
    }
}

// ---------------- reduce splits + row-normalize -> bf16 ctx ----------------
__global__ __launch_bounds__(256) void ctx_red(const ushort* __restrict__ pctx,
                                               const float* __restrict__ invZ,
                                               ushort* __restrict__ ctxb) {
  int t = blockIdx.x * 256 + threadIdx.x;
  int b = t >> 15;
  int r = (t & 32767) * 8;
  int d = r >> 9;
  float iz = invZ[b * 512 + d];
  const ushort* base = pctx + (size_t)b * 8 * 262144 + r;
  float f[8] = {};
#pragma unroll
  for (int s = 0; s < 8; s++) {
    uint4 v = *(const uint4*)(base + (size_t)s * 262144);
    uint w[4] = {v.x, v.y, v.z, v.w};
#pragma unroll
    for (int j = 0; j < 4; j++) {
      union { uint u; float f; } lo, hi;
      lo.u = w[j] << 16; hi.u = w[j] & 0xffff0000u;
      f[2 * j] += lo.f; f[2 * j + 1] += hi.f;
    }
  }
  uint o[4];
#pragma unroll
  for (int j = 0; j < 4; j++) o[j] = pk(f[2 * j] * iz, f[2 * j + 1] * iz);
  *(uint4*)(ctxb + (size_t)b * 262144 + r) = make_uint4(o[0], o[1], o[2], o[3]);
}

// ---------------- M GEMM: Mb[b,o,d] = SQK * sum_e pw[o,e] ctx[b,d,e] -------
__global__ __launch_bounds__(256) void m_gemm_bf16(
    const ushort* __restrict__ pwb, const ushort* __restrict__ ctxb,
    ushort* __restrict__ Mb) {
  __shared__ ushort As[4096], Bs[4096];
  int b = blockIdx.z, d0 = blockIdx.x * 64, o0 = blockIdx.y * 64;
  int tid = threadIdx.x;
  f32x4 acc[2][2] = {{{0.f, 0.f, 0.f, 0.f}}};
  mfma_loop64<CC, CC, CC>(pwb + (size_t)o0 * CC,
                          ctxb + (size_t)b * CC * CC + (size_t)d0 * CC, As, Bs, tid, acc);
  int wave = tid >> 6, lane = tid & 63;
  int wm = (wave >> 1) * 32, wn = (wave & 1) * 32;
  int col = lane & 15, rb = (lane >> 4) * 4;
#pragma unroll
  for (int m = 0; m < 2; m++)
#pragma unroll
    for (int n = 0; n < 2; n++)
#pragma unroll
      for (int j = 0; j < 4; j++) {
        int go = o0 + wm + m * 16 + rb + j;
        int gd = d0 + wn + n * 16 + col;
        Mb[((size_t)b * CC + go) * CC + gd] = f2bf(acc[m][n][j] * SQK);
      }
}

// ---------------- P GEMM: Pb[b,o,c] = sum_d Mb[b,o,d] wqT[c,d] -------------
__global__ __launch_bounds__(256) void p_gemm_bf16(
    const ushort* __restrict__ Mb, const ushort* __restrict__ wqT,
    ushort* __restrict__ Pb) {
  __shared__ ushort As[4096], Bs[4096];
  int b = blockIdx.z, c0 = blockIdx.x * 64, o0 = blockIdx.y * 64;
  int tid = threadIdx.x;
  f32x4 acc[2][2] = {{{0.f, 0.f, 0.f, 0.f}}};
  mfma_loop64<CC, CC, CC>(Mb + (size_t)b * CC * CC + (size_t)o0 * CC,
                          wqT + (size_t)c0 * CC, As, Bs, tid, acc);
  int wave = tid >> 6, lane = tid & 63;
  int wm = (wave >> 1) * 32, wn = (wave & 1) * 32;
  int col = lane & 15, rb = (lane >> 4) * 4;
#pragma unroll
  for (int m = 0; m < 2; m++)
#pragma unroll
    for (int n = 0; n < 2; n++)
#pragma unroll
      for (int j = 0; j < 4; j++) {
        int go = o0 + wm + m * 16 + rb + j;
        int gc = c0 + wn + n * 16 + col;
        Pb[((size_t)b * CC + go) * CC + gc] = f2bf(acc[m][n][j]);
      }
}

// ---------------- pb2[b,o] = sum_d Mb[b,o,d]*bq[d] + proj_b[o] -------------
__global__ __launch_bounds__(256) void pb2_kernel(
    const ushort* __restrict__ Mb, const float* __restrict__ qkv_b,
    const float* __restrict__ proj_b, float* __restrict__ pb2) {
  int b = blockIdx.x, og = blockIdx.y;
  int r = og * 64 + (threadIdx.x >> 2);
  int q = threadIdx.x & 3;
  const ushort* Mr = Mb + ((size_t)(b * CC + r)) * CC + q * 128;
  const float* bq = qkv_b + q * 128;
  float s = 0.f;
#pragma unroll
  for (int i = 0; i < 16; i++) {
    uint4 v = *(const uint4*)(Mr + i * 8);
    uint w[4] = {v.x, v.y, v.z, v.w};
#pragma unroll
    for (int j = 0; j < 4; j++) {
      union { uint u; float f; } lo, hi;
      lo.u = w[j] << 16; hi.u = w[j] & 0xffff0000u;
      s += lo.f * bq[i * 8 + 2 * j] + hi.f * bq[i * 8 + 2 * j + 1];
    }
  }
  s += __shfl_xor(s, 1);
  s += __shfl_xor(s, 2);
  if (q == 0) pb2[b * CC + r] = s + proj_b[r];
}

// --- final GEMM (128^2, 8-wave, 2 blocks/CU, XCD-swizzled) -----------------
__global__ __launch_bounds__(512) void final_gemm_bf16(
    const float* __restrict__ x, const ushort* __restrict__ Pb,
    const ushort* __restrict__ hT, const float* __restrict__ pb2,
    float* __restrict__ out) {
  extern __shared__ ushort lds[];
  ushort* As = lds;
  ushort* Bs = lds + 2 * 8192;
  int bx = blockIdx.x, by = blockIdx.y, bz = blockIdx.z;
  xcd_remap(32, 4, 1024, bx, by, bz);  // chunk=128 = one batch plane per XCD
  int b = bz, n0 = bx * 128, m0 = by * 128;
  int tid = threadIdx.x;
  f32x4 acc[4][2] = {{{0.f, 0.f, 0.f, 0.f}}};
  mfma128<8>(Pb + (size_t)b * CC * CC + (size_t)m0 * CC,
             hT + (size_t)b * NT * CC + (size_t)n0 * CC, CC, CC, As, Bs, tid, acc);
  int wave = tid >> 6, lane = tid & 63;
  int wr = wave >> 2, wc = wave & 3;
  int col = lane & 15, rb = (lane >> 4) * 4;
#pragma unroll
  for (int mi = 0; mi < 4; mi++)
#pragma unroll
    for (int j = 0; j < 4; j++) {
      int gm = m0 + wr * 64 + mi * 16 + rb + j;
      float bias = pb2[b * CC + gm];
      size_t rowoff = ((size_t)(b * CC + gm)) * NT + n0 + wc * 32 + col;
#pragma unroll
      for (int ni = 0; ni < 2; ni++)
        out[rowoff + ni * 16] = acc[mi][ni][j] + bias + x[rowoff + ni * 16];
    }
}

extern "C" void kernel_launch(void* const* d_in, const int* in_sizes, int n_in,
                              void* d_out, int out_size, void* d_ws, size_t ws_size,
                              hipStream_t stream) {
  const float* x        = (const float*)d_in[0];
  const float* qkv_w    = (const float*)d_in[1];
  const float* qkv_b    = (const float*)d_in[2];
  const float* proj_w   = (const float*)d_in[3];
  const float* proj_b   = (const float*)d_in[4];
  const float* gn_scale = (const float*)d_in[5];
  const float* gn_bias  = (const float*)d_in[6];
  float* out = (float*)d_out;
  float* ws  = (float*)d_ws;

  float*  red   = ws + OFF_RED;
  float*  pb2   = ws + OFF_PB2;
  float*  invZ  = ws + OFF_IZ;
  ushort* wkvb  = (ushort*)(ws + OFF_WKV);
  ushort* pwb   = (ushort*)(ws + OFF_PWB);
  ushort* wqT   = (ushort*)(ws + OFF_WQT);
  ushort* Mb    = (ushort*)(ws + OFF_MB);
  ushort* Pb    = (ushort*)(ws + OFF_PBF);
  ushort* ctxb  = (ushort*)(ws + OFF_CTXB);
  ushort* pctx  = (ushort*)(ws + OFF_PCTX);
  ushort* hT    = (ushort*)(ws + OFF_HT);
  ushort* kvb   = (ushort*)(ws + OFF_KVB);

  constexpr int DSM  = 4 * TBUF * 2;  // 131072 B (256^2 kernels)
  constexpr int DSM2 = 4 * 8192 * 2;  // 65536 B  (128^2 final)
  hipFuncSetAttribute((const void*)kv_gemm_bf16,
                      hipFuncAttributeMaxDynamicSharedMemorySize, DSM);
  hipFuncSetAttribute((const void*)ctx_gemm_split,
                      hipFuncAttributeMaxDynamicSharedMemorySize, DSM);
  hipFuncSetAttribute((const void*)final_gemm_bf16,
                      hipFuncAttributeMaxDynamicSharedMemorySize, DSM2);

  prep_kernel<<<1536, 256, 0, stream>>>(x, qkv_w, proj_w, red, wkvb, pwb, wqT);
  ht_kernel<<<dim3(64, 8, 8), 256, 0, stream>>>(x, red, gn_scale, gn_bias, hT);
  kv_gemm_bf16<<<dim3(16, 4, 8), 512, DSM, stream>>>(wkvb, hT, qkv_b, kvb);
  zred<<<4096, 256, 0, stream>>>(kvb, invZ);
  ctx_gemm_split<<<dim3(2, 2, 64), 512, DSM, stream>>>(kvb, pctx);
  ctx_red<<<1024, 256, 0, stream>>>(pctx, invZ, ctxb);
  m_gemm_bf16<<<dim3(8, 8, 8), 256, 0, stream>>>(pwb, ctxb, Mb);
  p_gemm_bf16<<<dim3(8, 8, 8), 256, 0, stream>>>(Mb, wqT, Pb);
  pb2_kernel<<<dim3(8, 8), 256, 0, stream>>>(Mb, qkv_b, proj_b, pb2);
  final_gemm_bf16<<<dim3(32, 4, 8), 512, DSM2, stream>>>(x, Pb, hT, pb2, out);
}

// Round 19
// 177.338 us; speedup vs baseline: 1.0683x; 1.0090x over previous
//
#include <hip/hip_runtime.h>

#define BB 8
#define CC 512
#define NT 4096
#define GG 8
#define CPG 64
#define EPSF 1e-6f
#define SQK 0.04419417382415922f  // 1/sqrt(512)

typedef __attribute__((ext_vector_type(8))) short bf16x8;
typedef __attribute__((ext_vector_type(4))) float f32x4;

// ws offsets (float units)
#define OFF_RED  0
#define OFF_PB2  4096
#define OFF_WKV  274432
#define OFF_PWB  536576
#define OFF_WQT  667648
#define OFF_MB   798720
#define OFF_PBF  1847296
#define OFF_CTXB 2895872
#define OFF_PCTX 3944448
#define OFF_HT   12333056
#define OFF_KVB  20721664
#define OFF_PZ   37498880   // 8*8*512 floats of split-partial Z, after kvb

__device__ __forceinline__ ushort f2bf(float f) {
  union { float f; uint u; } v; v.f = f;
  uint r = (v.u + 0x7fffu + ((v.u >> 16) & 1u)) >> 16;
  return (ushort)r;
}
__device__ __forceinline__ float bf2f(ushort h) {
  union { uint u; float f; } v; v.u = ((uint)h) << 16;
  return v.f;
}
__device__ __forceinline__ uint pk(float a, float b) {
  return (uint)f2bf(a) | ((uint)f2bf(b) << 16);
}
__device__ __forceinline__ void gload16(const ushort* g, ushort* l) {
  __builtin_amdgcn_global_load_lds((const __attribute__((address_space(1))) void*)g,
                                   (__attribute__((address_space(3))) void*)l, 16, 0, 0);
}
#define KSWZ(kofs, row) ((kofs) ^ ((((row) >> 1) & 3) << 3))

// XCD-aware bijective remap (m204)
__device__ __forceinline__ void xcd_remap(int gx, int gy, int N,
                                          int& bx, int& by, int& bz) {
  int h = bx + gx * (by + gy * bz);
  int l = ((h & 7) * (N >> 3)) + (h >> 3);
  bx = l % gx;
  int t = l / gx;
  by = t % gy;
  bz = t / gy;
}

// ---- fused prep: GN partial stats + weight converts + Wq^T (1536 blocks) --
__global__ __launch_bounds__(256) void prep_kernel(
    const float* __restrict__ x, const float* __restrict__ qkv_w,
    const float* __restrict__ proj_w, float* __restrict__ red,
    ushort* __restrict__ wkvb, ushort* __restrict__ pwb,
    ushort* __restrict__ wqT) {
  int bid = blockIdx.x;
  int tid = threadIdx.x;
  if (bid < 512) {
    int bg = bid >> 3, chunk = bid & 7;
    const float4* p4 = (const float4*)(x + (size_t)bg * (CPG * NT) + (size_t)chunk * 32768);
    float s = 0.f, sq = 0.f;
    for (int i = tid; i < 8192; i += 256) {
      float4 v = p4[i];
      s  += v.x + v.y + v.z + v.w;
      sq += v.x * v.x + v.y * v.y + v.z * v.z + v.w * v.w;
    }
    for (int off = 32; off > 0; off >>= 1) {
      s  += __shfl_down(s, off);
      sq += __shfl_down(sq, off);
    }
    __shared__ float ls[4], lq[4];
    int wid = tid >> 6, lane = tid & 63;
    if (lane == 0) { ls[wid] = s; lq[wid] = sq; }
    __syncthreads();
    if (tid == 0) {
      red[(bg * 8 + chunk) * 2]     = ls[0] + ls[1] + ls[2] + ls[3];
      red[(bg * 8 + chunk) * 2 + 1] = lq[0] + lq[1] + lq[2] + lq[3];
    }
  } else if (bid < 1024) {
    int idx = ((bid - 512) * 256 + tid) * 4;
    float4 v = *(const float4*)(qkv_w + (size_t)CC * CC + idx);
    *(uint2*)(wkvb + idx) = make_uint2(pk(v.x, v.y), pk(v.z, v.w));
  } else if (bid < 1280) {
    int idx = ((bid - 1024) * 256 + tid) * 4;
    float4 v = *(const float4*)(proj_w + idx);
    *(uint2*)(pwb + idx) = make_uint2(pk(v.x, v.y), pk(v.z, v.w));
  } else {
    __shared__ float t[32][33];
    int tt = bid - 1280;
    int c0 = (tt & 15) * 32, d0 = (tt >> 4) * 32;
    int r = tid >> 3, c4 = (tid & 7) * 4;
    float4 v = *(const float4*)(qkv_w + (size_t)(d0 + r) * CC + c0 + c4);
    t[r][c4] = v.x; t[r][c4 + 1] = v.y; t[r][c4 + 2] = v.z; t[r][c4 + 3] = v.w;
    __syncthreads();
    int r2 = tid >> 3, d4 = (tid & 7) * 4;
    uint w0 = pk(t[d4][r2], t[d4 + 1][r2]);
    uint w1 = pk(t[d4 + 2][r2], t[d4 + 3][r2]);
    *(uint2*)&wqT[(size_t)(c0 + r2) * CC + d0 + d4] = make_uint2(w0, w1);
  }
}

// ---------------- h^T in bf16 (with inline GN finalize) --------------------
__global__ __launch_bounds__(256) void ht_kernel(
    const float* __restrict__ x, const float* __restrict__ red,
    const float* __restrict__ gn_scale, const float* __restrict__ gn_bias,
    ushort* __restrict__ hT) {
  __shared__ float ts[64][68];
  __shared__ float la[64], lb[64];
  int b = blockIdx.z, g = blockIdx.y, n0 = blockIdx.x * 64;
  int c0 = g * 64;
  int tid = threadIdx.x;
  if (tid == 0) {
    int bg = b * 8 + g;
    float s = 0.f, sq = 0.f;
#pragma unroll
    for (int i = 0; i < 8; i++) {
      s  += red[(bg * 8 + i) * 2];
      sq += red[(bg * 8 + i) * 2 + 1];
    }
    float mean = s / (float)(CPG * NT);
    float var  = sq / (float)(CPG * NT) - mean * mean;
    ts[0][0] = mean; ts[0][1] = rsqrtf(var + EPSF);
  }
  __syncthreads();
  if (tid < 64) {
    float mean = ts[0][0], rstd = ts[0][1];
    float a = gn_scale[c0 + tid] * rstd;
    la[tid] = a;
    lb[tid] = gn_bias[c0 + tid] - mean * a;
  }
  __syncthreads();
  int tn = (tid & 15) * 4, tc = tid >> 4;
#pragma unroll
  for (int it = 0; it < 4; it++) {
    int c = tc + it * 16;
    float a  = la[c];
    float bb = lb[c];
    float4 v = *(const float4*)(x + ((size_t)(b * CC + c0 + c)) * NT + n0 + tn);
    ts[c][tn]     = a * v.x + bb;
    ts[c][tn + 1] = a * v.y + bb;
    ts[c][tn + 2] = a * v.z + bb;
    ts[c][tn + 3] = a * v.w + bb;
  }
  __syncthreads();
#pragma unroll
  for (int it = 0; it < 2; it++) {
    int idx = tid + it * 256;
    int n = idx >> 3, c8 = (idx & 7) * 8;
    uint w[4];
#pragma unroll
    for (int j = 0; j < 4; j++)
      w[j] = pk(ts[c8 + 2 * j][n], ts[c8 + 2 * j + 1][n]);
    *(uint4*)&hT[((size_t)b * NT + n0 + n) * CC + c0 + c8] = make_uint4(w[0], w[1], w[2], w[3]);
  }
}

#define TBUF 16384  // ushorts per 256x64 buffer

// ===== coarse 256x256 loop: BK=64, 2-buf, 1-deep prefetch ==================
// ZSUM: accumulate row sums of the A operand (bf16 fragments) into zacc[8];
// VALU-only work hidden under the MFMA pipe (separate pipes, m114).
__device__ __forceinline__ void stage256(const ushort* __restrict__ G, ushort* L,
                                         int LD, int wave, int lane) {
  int rw = wave * 8 + (lane >> 3);
  int cg = lane & 7;
#pragma unroll
  for (int s = 0; s < 4; s++) {
    int row = s * 64 + rw;
    int gcol = (cg ^ (row & 7)) * 8;
    gload16(G + (size_t)row * LD + gcol, L + s * 4096 + wave * 512);
  }
}

template <int NTILES, bool ZSUM>
__device__ __forceinline__ void mfma256c(const ushort* __restrict__ A,
                                         const ushort* __restrict__ B,
                                         int LDA, int LDB, ushort* As, ushort* Bs,
                                         int tid, f32x4 acc[8][4], float* zacc) {
  int wave = tid >> 6, lane = tid & 63;
  int wr = wave >> 2, wc = wave & 3;
  stage256(A, As, LDA, wave, lane);
  stage256(B, Bs, LDB, wave, lane);
  const ushort* gA = A + 64;
  const ushort* gB = B + 64;
  int rowA = wr * 128 + (lane & 15);
  int rowB = wc * 64 + (lane & 15);
  int kg0 = lane >> 4;
#pragma unroll 1
  for (int t = 0; t < NTILES; t++) {
    __builtin_amdgcn_s_barrier();
    asm volatile("" ::: "memory");
    if (t + 1 < NTILES) {
      stage256(gA, As + ((t + 1) & 1) * TBUF, LDA, wave, lane);
      stage256(gB, Bs + ((t + 1) & 1) * TBUF, LDB, wave, lane);
      gA += 64; gB += 64;
      asm volatile("s_waitcnt vmcnt(8)" ::: "memory");
    } else {
      asm volatile("s_waitcnt vmcnt(0)" ::: "memory");
    }
    __builtin_amdgcn_s_barrier();
    asm volatile("" ::: "memory");
    const ushort* Ab = As + (t & 1) * TBUF;
    const ushort* Bb = Bs + (t & 1) * TBUF;
#pragma unroll
    for (int kk = 0; kk < 2; kk++) {
      int kg = kg0 + kk * 4;
      bf16x8 bfr[4];
#pragma unroll
      for (int ni = 0; ni < 4; ni++) {
        int r = rowB + ni * 16;
        bfr[ni] = *(const bf16x8*)(Bb + r * 64 + ((kg ^ (r & 7)) << 3));
      }
#pragma unroll
      for (int mi = 0; mi < 8; mi++) {
        int r = rowA + mi * 16;
        bf16x8 afr = *(const bf16x8*)(Ab + r * 64 + ((kg ^ (r & 7)) << 3));
        if (ZSUM) {
          const uint* au = (const uint*)&afr;
          float zs = 0.f;
#pragma unroll
          for (int q = 0; q < 4; q++) {
            union { uint u; float f; } lo, hi;
            lo.u = au[q] << 16; hi.u = au[q] & 0xffff0000u;
            zs += lo.f + hi.f;
          }
          zacc[mi] += zs;
        }
#pragma unroll
        for (int ni = 0; ni < 4; ni++)
          acc[mi][ni] = __builtin_amdgcn_mfma_f32_16x16x32_bf16(afr, bfr[ni], acc[mi][ni], 0, 0, 0);
      }
    }
  }
}

// ===== 128x128 loop: BK=64, 8 waves (2Mx4N, wave tile 64x32), 64KB LDS =====
__device__ __forceinline__ void stage128(const ushort* __restrict__ G, ushort* L,
                                         int LD, int tid) {
#pragma unroll
  for (int s = 0; s < 2; s++) {
    int row = s * 64 + (tid >> 3);
    int gcol = ((tid & 7) ^ (row & 7)) * 8;  // pre-swizzled global col
    gload16(G + (size_t)row * LD + gcol, L + s * 4096 + (tid >> 6) * 512);
  }
}

template <int NTILES>
__device__ __forceinline__ void mfma128(const ushort* __restrict__ A,
                                        const ushort* __restrict__ B,
                                        int LDA, int LDB, ushort* As, ushort* Bs,
                                        int tid, f32x4 acc[4][2]) {
  int wave = tid >> 6, lane = tid & 63;
  int wr = wave >> 2, wc = wave & 3;
  stage128(A, As, LDA, tid);
  stage128(B, Bs, LDB, tid);
  const ushort* gA = A + 64;
  const ushort* gB = B + 64;
  int rowA = wr * 64 + (lane & 15);
  int rowB = wc * 32 + (lane & 15);
  int kg0 = lane >> 4;
#pragma unroll 1
  for (int t = 0; t < NTILES; t++) {
    __builtin_amdgcn_s_barrier();
    asm volatile("" ::: "memory");
    if (t + 1 < NTILES) {
      stage128(gA, As + ((t + 1) & 1) * 8192, LDA, tid);
      stage128(gB, Bs + ((t + 1) & 1) * 8192, LDB, tid);
      gA += 64; gB += 64;
      asm volatile("s_waitcnt vmcnt(4)" ::: "memory");  // current tile landed
    } else {
      asm volatile("s_waitcnt vmcnt(0)" ::: "memory");
    }
    __builtin_amdgcn_s_barrier();
    asm volatile("" ::: "memory");
    const ushort* Ab = As + (t & 1) * 8192;
    const ushort* Bb = Bs + (t & 1) * 8192;
#pragma unroll
    for (int kk = 0; kk < 2; kk++) {
      int kg = kg0 + kk * 4;
      bf16x8 bfr[2];
#pragma unroll
      for (int ni = 0; ni < 2; ni++) {
        int r = rowB + ni * 16;
        bfr[ni] = *(const bf16x8*)(Bb + r * 64 + ((kg ^ (r & 7)) << 3));
      }
#pragma unroll
      for (int mi = 0; mi < 4; mi++) {
        int r = rowA + mi * 16;
        bf16x8 afr = *(const bf16x8*)(Ab + r * 64 + ((kg ^ (r & 7)) << 3));
#pragma unroll
        for (int ni = 0; ni < 2; ni++)
          acc[mi][ni] = __builtin_amdgcn_mfma_f32_16x16x32_bf16(afr, bfr[ni], acc[mi][ni], 0, 0, 0);
      }
    }
  }
}

// ------- 64x64 MFMA mainloop (m/p GEMMs), unchanged ------------------------
template <int KTOT, int LDA, int LDB>
__device__ __forceinline__ void mfma_loop64(const ushort* __restrict__ A,
                                            const ushort* __restrict__ B,
                                            ushort* As, ushort* Bs, int tid,
                                            f32x4 acc[2][2]) {
  int wave = tid >> 6, lane = tid & 63;
  int srow = tid >> 2;
  int kofs = KSWZ((tid & 3) * 8, srow & 15);
  const ushort* ga = A + (size_t)srow * LDA + kofs;
  const ushort* gb = B + (size_t)srow * LDB + kofs;
  int lo = wave * 512;
  int wm = (wave >> 1) * 32, wn = (wave & 1) * 32;
  int rowl = lane & 15;
  int kread = KSWZ((lane >> 4) * 8, rowl);
  int aoff = (wm + rowl) * 32 + kread;
  int boff = (wn + rowl) * 32 + kread;
  constexpr int NIT = KTOT / 32;
  gload16(ga, As + lo); gload16(gb, Bs + lo);
  ga += 32; gb += 32;
#pragma unroll 1
  for (int t = 0; t < NIT; t++) {
    int cb = (t & 1) * 2048;
    int nb = 2048 - cb;
    if (t + 1 < NIT) {
      gload16(ga, As + nb + lo); gload16(gb, Bs + nb + lo);
      ga += 32; gb += 32;
      asm volatile("s_waitcnt vmcnt(2)" ::: "memory");
    } else {
      asm volatile("s_waitcnt vmcnt(0)" ::: "memory");
    }
    __builtin_amdgcn_s_barrier();
    asm volatile("" ::: "memory");
    bf16x8 a[2], b[2];
#pragma unroll
    for (int m = 0; m < 2; m++) a[m] = *(const bf16x8*)(As + cb + aoff + m * 512);
#pragma unroll
    for (int n = 0; n < 2; n++) b[n] = *(const bf16x8*)(Bs + cb + boff + n * 512);
#pragma unroll
    for (int m = 0; m < 2; m++)
#pragma unroll
      for (int n = 0; n < 2; n++)
        acc[m][n] = __builtin_amdgcn_mfma_f32_16x16x32_bf16(a[m], b[n], acc[m][n], 0, 0, 0);
    asm volatile("" ::: "memory");
    __builtin_amdgcn_s_barrier();
    asm volatile("" ::: "memory");
  }
}

// --- kv GEMM bf16 (256^2, coarse, XCD-swizzled) + fused exp on k-rows ------
__global__ __launch_bounds__(512) void kv_gemm_bf16(
    const ushort* __restrict__ wkvb, const ushort* __restrict__ hT,
    const float* __restrict__ qkv_b, ushort* __restrict__ kvb) {
  extern __shared__ ushort lds[];
  ushort* As = lds;
  ushort* Bs = lds + 2 * TBUF;
  int bx = blockIdx.x, by = blockIdx.y, bz = blockIdx.z;
  xcd_remap(16, 4, 512, bx, by, bz);   // chunk=64 = one batch plane per XCD
  int b = bz, n0 = bx * 256, m0 = by * 256;
  int tid = threadIdx.x;
  f32x4 acc[8][4] = {{{0.f, 0.f, 0.f, 0.f}}};
  mfma256c<8, false>(wkvb + (size_t)m0 * CC, hT + (size_t)b * NT * CC + (size_t)n0 * CC,
                     CC, CC, As, Bs, tid, acc, nullptr);
  int wave = tid >> 6, lane = tid & 63;
  int wr = wave >> 2, wc = wave & 3;
  int col = lane & 15, rb = (lane >> 4) * 4;
  bool isK = (m0 < 512);
#pragma unroll
  for (int mi = 0; mi < 8; mi++)
#pragma unroll
    for (int j = 0; j < 4; j++) {
      int gm = m0 + wr * 128 + mi * 16 + rb + j;
      float bias = qkv_b[CC + gm];
      ushort* orow = kvb + ((size_t)(b * 1024 + gm)) * NT + n0 + wc * 64 + col;
#pragma unroll
      for (int ni = 0; ni < 4; ni++) {
        float val = acc[mi][ni][j] + bias;
        if (isK) val = __expf(val);  // softmax shift-invariant; |k|<~6
        orow[ni * 16] = f2bf(val);
      }
    }
}

// --- ctx split-K (256^2, coarse, XCD-swizzled) + fused Z row-sums ----------
// pctx[b,s,d,e] = sum_{n in split s} ek[d,n] v[e,n]; blocks with e0==0 also
// emit pZ[b,s,d] = sum_{n in split s} ek[d,n] (A-fragment sums, VALU-hidden).
__global__ __launch_bounds__(512) void ctx_gemm_split(
    const ushort* __restrict__ kvb, ushort* __restrict__ pctx,
    float* __restrict__ pZ) {
  extern __shared__ ushort lds[];
  ushort* As = lds;
  ushort* Bs = lds + 2 * TBUF;
  int bx = blockIdx.x, by = blockIdx.y, bz = blockIdx.z;
  xcd_remap(2, 2, 256, bx, by, bz);    // chunk=32 = 8 (b,s) slices per XCD
  int e0 = bx * 256, d0 = by * 256;
  int b = bz >> 3, s = bz & 7;
  int tid = threadIdx.x;
  f32x4 acc[8][4] = {{{0.f, 0.f, 0.f, 0.f}}};
  float zacc[8] = {0.f, 0.f, 0.f, 0.f, 0.f, 0.f, 0.f, 0.f};
  const ushort* K = kvb + (size_t)b * 1024 * NT + (size_t)d0 * NT + s * 512;
  const ushort* V = kvb + ((size_t)b * 1024 + 512) * NT + (size_t)e0 * NT + s * 512;
  mfma256c<8, true>(K, V, NT, NT, As, Bs, tid, acc, zacc);
  int wave = tid >> 6, lane = tid & 63;
  int wr = wave >> 2, wc = wave & 3;
  int col = lane & 15, rb = (lane >> 4) * 4;
  // Z: reduce across the 4 kg lanes (same lane&15), write once per row.
  if (e0 == 0) {
#pragma unroll
    for (int mi = 0; mi < 8; mi++) {
      float z = zacc[mi];
      z += __shfl_xor(z, 16);
      z += __shfl_xor(z, 32);
      if (wc == 0 && (lane >> 4) == 0)
        pZ[((size_t)(b * 8 + s)) * 512 + d0 + wr * 128 + mi * 16 + (lane & 15)] = z;
    }
  }
#pragma unroll
  for (int mi = 0; mi < 8; mi++)
#pragma unroll
    for (int j = 0; j < 4; j++) {
      int gd = d0 + wr * 128 + mi * 16 + rb + j;
      ushort* orow = pctx + ((size_t)(b * 8 + s) * CC + gd) * CC + e0 + wc * 64 + col;
#pragma unroll
      for (int ni = 0; ni < 4; ni++)
        orow[ni * 16] = f2bf(acc[mi][ni][j]);
    }
}

// -------- reduce splits + row-normalize (invZ from pZ) -> bf16 ctx ---------
__global__ __launch_bounds__(256) void ctx_red(const ushort* __restrict__ pctx,
                                               const float* __restrict__ pZ,
                                               ushort* __restrict__ ctxb) {
  int t = blockIdx.x * 256 + threadIdx.x;
  int b = t >> 15;
  int r = (t & 32767) * 8;
  int d = r >> 9;
  float zs = 0.f;
#pragma unroll
  for (int s = 0; s < 8; s++) zs += pZ[((size_t)(b * 8 + s)) * 512 + d];
  float iz = 1.f / zs;
  const ushort* base = pctx + (size_t)b * 8 * 262144 + r;
  float f[8] = {};
#pragma unroll
  for (int s = 0; s < 8; s++) {
    uint4 v = *(const uint4*)(base + (size_t)s * 262144);
    uint w[4] = {v.x, v.y, v.z, v.w};
#pragma unroll
    for (int j = 0; j < 4; j++) {
      union { uint u; float f; } lo, hi;
      lo.u = w[j] << 16; hi.u = w[j] & 0xffff0000u;
      f[2 * j] += lo.f; f[2 * j + 1] += hi.f;
    }
  }
  uint o[4];
#pragma unroll
  for (int j = 0; j < 4; j++) o[j] = pk(f[2 * j] * iz, f[2 * j + 1] * iz);
  *(uint4*)(ctxb + (size_t)b * 262144 + r) = make_uint4(o[0], o[1], o[2], o[3]);
}

// ---------------- M GEMM: Mb[b,o,d] = SQK * sum_e pw[o,e] ctx[b,d,e] -------
__global__ __launch_bounds__(256) void m_gemm_bf16(
    const ushort* __restrict__ pwb, const ushort* __restrict__ ctxb,
    ushort* __restrict__ Mb) {
  __shared__ ushort As[4096], Bs[4096];
  int b = blockIdx.z, d0 = blockIdx.x * 64, o0 = blockIdx.y * 64;
  int tid = threadIdx.x;
  f32x4 acc[2][2] = {{{0.f, 0.f, 0.f, 0.f}}};
  mfma_loop64<CC, CC, CC>(pwb + (size_t)o0 * CC,
                          ctxb + (size_t)b * CC * CC + (size_t)d0 * CC, As, Bs, tid, acc);
  int wave = tid >> 6, lane = tid & 63;
  int wm = (wave >> 1) * 32, wn = (wave & 1) * 32;
  int col = lane & 15, rb = (lane >> 4) * 4;
#pragma unroll
  for (int m = 0; m < 2; m++)
#pragma unroll
    for (int n = 0; n < 2; n++)
#pragma unroll
      for (int j = 0; j < 4; j++) {
        int go = o0 + wm + m * 16 + rb + j;
        int gd = d0 + wn + n * 16 + col;
        Mb[((size_t)b * CC + go) * CC + gd] = f2bf(acc[m][n][j] * SQK);
      }
}

// ---------------- P GEMM: Pb[b,o,c] = sum_d Mb[b,o,d] wqT[c,d] -------------
__global__ __launch_bounds__(256) void p_gemm_bf16(
    const ushort* __restrict__ Mb, const ushort* __restrict__ wqT,
    ushort* __restrict__ Pb) {
  __shared__ ushort As[4096], Bs[4096];
  int b = blockIdx.z, c0 = blockIdx.x * 64, o0 = blockIdx.y * 64;
  int tid = threadIdx.x;
  f32x4 acc[2][2] = {{{0.f, 0.f, 0.f, 0.f}}};
  mfma_loop64<CC, CC, CC>(Mb + (size_t)b * CC * CC + (size_t)o0 * CC,
                          wqT + (size_t)c0 * CC, As, Bs, tid, acc);
  int wave = tid >> 6, lane = tid & 63;
  int wm = (wave >> 1) * 32, wn = (wave & 1) * 32;
  int col = lane & 15, rb = (lane >> 4) * 4;
#pragma unroll
  for (int m = 0; m < 2; m++)
#pragma unroll
    for (int n = 0; n < 2; n++)
#pragma unroll
      for (int j = 0; j < 4; j++) {
        int go = o0 + wm + m * 16 + rb + j;
        int gc = c0 + wn + n * 16 + col;
        Pb[((size_t)b * CC + go) * CC + gc] = f2bf(acc[m][n][j]);
      }
}

// ---------------- pb2[b,o] = sum_d Mb[b,o,d]*bq[d] + proj_b[o] -------------
__global__ __launch_bounds__(256) void pb2_kernel(
    const ushort* __restrict__ Mb, const float* __restrict__ qkv_b,
    const float* __restrict__ proj_b, float* __restrict__ pb2) {
  int b = blockIdx.x, og = blockIdx.y;
  int r = og * 64 + (threadIdx.x >> 2);
  int q = threadIdx.x & 3;
  const ushort* Mr = Mb + ((size_t)(b * CC + r)) * CC + q * 128;
  const float* bq = qkv_b + q * 128;
  float s = 0.f;
#pragma unroll
  for (int i = 0; i < 16; i++) {
    uint4 v = *(const uint4*)(Mr + i * 8);
    uint w[4] = {v.x, v.y, v.z, v.w};
#pragma unroll
    for (int j = 0; j < 4; j++) {
      union { uint u; float f; } lo, hi;
      lo.u = w[j] << 16; hi.u = w[j] & 0xffff0000u;
      s += lo.f * bq[i * 8 + 2 * j] + hi.f * bq[i * 8 + 2 * j + 1];
    }
  }
  s += __shfl_xor(s, 1);
  s += __shfl_xor(s, 2);
  if (q == 0) pb2[b * CC + r] = s + proj_b[r];
}

// --- final GEMM (128^2, 8-wave, 2 blocks/CU, XCD-swizzled) -----------------
__global__ __launch_bounds__(512) void final_gemm_bf16(
    const float* __restrict__ x, const ushort* __restrict__ Pb,
    const ushort* __restrict__ hT, const float* __restrict__ pb2,
    float* __restrict__ out) {
  extern __shared__ ushort lds[];
  ushort* As = lds;
  ushort* Bs = lds + 2 * 8192;
  int bx = blockIdx.x, by = blockIdx.y, bz = blockIdx.z;
  xcd_remap(32, 4, 1024, bx, by, bz);  // chunk=128 = one batch plane per XCD
  int b = bz, n0 = bx * 128, m0 = by * 128;
  int tid = threadIdx.x;
  f32x4 acc[4][2] = {{{0.f, 0.f, 0.f, 0.f}}};
  mfma128<8>(Pb + (size_t)b * CC * CC + (size_t)m0 * CC,
             hT + (size_t)b * NT * CC + (size_t)n0 * CC, CC, CC, As, Bs, tid, acc);
  int wave = tid >> 6, lane = tid & 63;
  int wr = wave >> 2, wc = wave & 3;
  int col = lane & 15, rb = (lane >> 4) * 4;
#pragma unroll
  for (int mi = 0; mi < 4; mi++)
#pragma unroll
    for (int j = 0; j < 4; j++) {
      int gm = m0 + wr * 64 + mi * 16 + rb + j;
      float bias = pb2[b * CC + gm];
      size_t rowoff = ((size_t)(b * CC + gm)) * NT + n0 + wc * 32 + col;
#pragma unroll
      for (int ni = 0; ni < 2; ni++)
        out[rowoff + ni * 16] = acc[mi][ni][j] + bias + x[rowoff + ni * 16];
    }
}

extern "C" void kernel_launch(void* const* d_in, const int* in_sizes, int n_in,
                              void* d_out, int out_size, void* d_ws, size_t ws_size,
                              hipStream_t stream) {
  const float* x        = (const float*)d_in[0];
  const float* qkv_w    = (const float*)d_in[1];
  const float* qkv_b    = (const float*)d_in[2];
  const float* proj_w   = (const float*)d_in[3];
  const float* proj_b   = (const float*)d_in[4];
  const float* gn_scale = (const float*)d_in[5];
  const float* gn_bias  = (const float*)d_in[6];
  float* out = (float*)d_out;
  float* ws  = (float*)d_ws;

  float*  red   = ws + OFF_RED;
  float*  pb2   = ws + OFF_PB2;
  float*  pZ    = ws + OFF_PZ;
  ushort* wkvb  = (ushort*)(ws + OFF_WKV);
  ushort* pwb   = (ushort*)(ws + OFF_PWB);
  ushort* wqT   = (ushort*)(ws + OFF_WQT);
  ushort* Mb    = (ushort*)(ws + OFF_MB);
  ushort* Pb    = (ushort*)(ws + OFF_PBF);
  ushort* ctxb  = (ushort*)(ws + OFF_CTXB);
  ushort* pctx  = (ushort*)(ws + OFF_PCTX);
  ushort* hT    = (ushort*)(ws + OFF_HT);
  ushort* kvb   = (ushort*)(ws + OFF_KVB);

  constexpr int DSM  = 4 * TBUF * 2;  // 131072 B (256^2 kernels)
  constexpr int DSM2 = 4 * 8192 * 2;  // 65536 B  (128^2 final)
  hipFuncSetAttribute((const void*)kv_gemm_bf16,
                      hipFuncAttributeMaxDynamicSharedMemorySize, DSM);
  hipFuncSetAttribute((const void*)ctx_gemm_split,
                      hipFuncAttributeMaxDynamicSharedMemorySize, DSM);
  hipFuncSetAttribute((const void*)final_gemm_bf16,
                      hipFuncAttributeMaxDynamicSharedMemorySize, DSM2);

  prep_kernel<<<1536, 256, 0, stream>>>(x, qkv_w, proj_w, red, wkvb, pwb, wqT);
  ht_kernel<<<dim3(64, 8, 8), 256, 0, stream>>>(x, red, gn_scale, gn_bias, hT);
  kv_gemm_bf16<<<dim3(16, 4, 8), 512, DSM, stream>>>(wkvb, hT, qkv_b, kvb);
  ctx_gemm_split<<<dim3(2, 2, 64), 512, DSM, stream>>>(kvb, pctx, pZ);
  ctx_red<<<1024, 256, 0, stream>>>(pctx, pZ, ctxb);
  m_gemm_bf16<<<dim3(8, 8, 8), 256, 0, stream>>>(pwb, ctxb, Mb);
  p_gemm_bf16<<<dim3(8, 8, 8), 256, 0, stream>>>(Mb, wqT, Pb);
  pb2_kernel<<<dim3(8, 8), 256, 0, stream>>>(Mb, qkv_b, proj_b, pb2);
  final_gemm_bf16<<<dim3(32, 4, 8), 512, DSM2, stream>>>(x, Pb, hT, pb2, out);
}